// Round 5
// baseline (1068.798 us; speedup 1.0000x reference)
//
#include <hip/hip_runtime.h>
#include <stdint.h>

// GNN: 2-layer GCN + skip + classifier head. All fp32 in/out; edge_index int32.
// N=100000, E=1600000, F=H=128, OUT=40.
//
//   h'[j] = dinv[j] * (A_in @ W)[j]  -> stored BF16 (dinv folded: no per-edge dinv load)
//   out[i] = relu(dinv[i] * sum_{j in N(i)} h'[j] + b) (+ skip)   [aggregate]
//   final = (out1 + out2) @ Wc + bc   (fp32)
//
// CSR build = two-level counting sort (391 buckets of 256 nodes; LDS scatter in pass 2)
// to avoid the 109 MB write-amplification of direct random 4B scatters.

#define HID 128
#define OUTD 40
#define BSH 8                 // 256 nodes per bucket
#define BCAP 6144             // LDS colbuf entries per bucket (mean ~4350, 28-sigma margin)

__device__ inline uint16_t f32_to_bf16(float f) {
    uint32_t u = __float_as_uint(f);
    uint32_t r = u + 0x7FFFu + ((u >> 16) & 1u);
    return (uint16_t)(r >> 16);
}

// ---------------- CSR build ----------------

__global__ void gnn_count_k(const int* __restrict__ edges, int* __restrict__ cnt, int E) {
    int t = blockIdx.x * 256 + threadIdx.x;
    if (t < E) atomicAdd(&cnt[edges[E + t]], 1);
}

// block-level inclusive scan of (cnt[i]+1)  (+1 = self loop)
__global__ void gnn_scan_block_k(const int* __restrict__ cnt, int* __restrict__ scanbuf,
                                 int* __restrict__ bsum, int n) {
    __shared__ int s[256];
    int i = blockIdx.x * 256 + threadIdx.x;
    int v = (i < n) ? (cnt[i] + 1) : 0;
    s[threadIdx.x] = v;
    __syncthreads();
    for (int off = 1; off < 256; off <<= 1) {
        int t = 0;
        if (threadIdx.x >= off) t = s[threadIdx.x - off];
        __syncthreads();
        if (threadIdx.x >= off) s[threadIdx.x] += t;
        __syncthreads();
    }
    if (i < n) scanbuf[i] = s[threadIdx.x];
    if (threadIdx.x == 255) bsum[blockIdx.x] = s[255];
}

__global__ void gnn_scan_bsum_k(int* __restrict__ bsum, int nb) {
    __shared__ int s[512];
    int v = (threadIdx.x < nb) ? bsum[threadIdx.x] : 0;
    s[threadIdx.x] = v;
    __syncthreads();
    for (int off = 1; off < 512; off <<= 1) {
        int t = 0;
        if (threadIdx.x >= off) t = s[threadIdx.x - off];
        __syncthreads();
        if (threadIdx.x >= off) s[threadIdx.x] += t;
        __syncthreads();
    }
    if (threadIdx.x < nb) bsum[threadIdx.x] = s[threadIdx.x];
}

// writes rowptr, per-bucket pair cursors (pcur), and dinv in one pass
__global__ void gnn_write_rowptr_k(const int* __restrict__ scanbuf, const int* __restrict__ bsum,
                                   const int* __restrict__ cnt, int* __restrict__ rowptr,
                                   int* __restrict__ pcur, float* __restrict__ dinv, int n) {
    int i = blockIdx.x * 256 + threadIdx.x;
    if (i == 0) { rowptr[0] = 0; pcur[0] = 0; }
    if (i < n) {
        int blk = i >> 8;
        int off = (blk > 0) ? bsum[blk - 1] : 0;
        int v = scanbuf[i] + off;
        rowptr[i + 1] = v;
        if (((i + 1) & 255) == 0) pcur[(i + 1) >> BSH] = v - (i + 1);  // bucket pair-start
        dinv[i] = rsqrtf((float)(cnt[i] + 1));
    }
}

// pass 1: scatter (src,dst) into per-bucket append streams (writes ~= E*8B, no amplification)
__global__ void gnn_bucket_scatter_k(const int* __restrict__ edges, int* __restrict__ pcur,
                                     int2* __restrict__ pairbuf, int E) {
    int t = blockIdx.x * 256 + threadIdx.x;
    if (t < E) {
        int src = edges[t];
        int dst = edges[E + t];
        int pos = atomicAdd(&pcur[dst >> BSH], 1);
        pairbuf[pos] = make_int2(src, dst);
    }
}

// pass 2: one block per bucket; scatter within bucket in LDS, write colidx coalesced.
// Self-loop occupies slot 0 of each node's segment.
__global__ __launch_bounds__(256) void gnn_build_csr_k(const int2* __restrict__ pairbuf,
                                                       const int* __restrict__ rowptr,
                                                       int* __restrict__ colidx,
                                                       int* __restrict__ gcur, int n) {
    __shared__ int cur[256];
    __shared__ int colbuf[BCAP];
    int b = blockIdx.x;
    int nb0 = b << BSH;
    int nb1 = min(n, nb0 + 256);
    int nn = nb1 - nb0;
    int segbeg = rowptr[nb0];
    int segend = rowptr[nb1];
    int seglen = segend - segbeg;
    int pairbeg = segbeg - nb0;
    int npairs = (segend - nb1) - pairbeg;

    if (seglen <= BCAP) {
        if (threadIdx.x < nn) {
            int node = nb0 + threadIdx.x;
            int rel = rowptr[node] - segbeg;
            colbuf[rel] = node;            // self loop
            cur[threadIdx.x] = rel + 1;
        }
        __syncthreads();
        for (int p = threadIdx.x; p < npairs; p += 256) {
            int2 pr = pairbuf[pairbeg + p];
            int pos = atomicAdd(&cur[pr.y - nb0], 1);
            colbuf[pos] = pr.x;
        }
        __syncthreads();
        for (int i = threadIdx.x; i < seglen; i += 256)
            colidx[segbeg + i] = colbuf[i];
    } else {
        // overflow fallback (statistically never taken): global scatter, gcur pre-zeroed
        if (threadIdx.x < nn) {
            int node = nb0 + threadIdx.x;
            colidx[rowptr[node]] = node;
        }
        __syncthreads();
        for (int p = threadIdx.x; p < npairs; p += 256) {
            int2 pr = pairbuf[pairbeg + p];
            int pos = atomicAdd(&gcur[pr.y], 1);
            colidx[rowptr[pr.y] + 1 + pos] = pr.x;
        }
    }
}

// ---------------- GEMM [n,128] @ [128,128], row-scaled by dinv -> bf16 h' ----------------
// 32 rows x 128 cols per block; 256 threads; each thread 4 rows x 4 cols.

__global__ __launch_bounds__(256) void gnn_gemm128_k(const float* __restrict__ A,
                                                     const float* __restrict__ W,
                                                     const float* __restrict__ dinv,
                                                     uint16_t* __restrict__ outh, int n) {
    __shared__ float a[32][HID];  // 16 KB
    const int tx = threadIdx.x & 31;
    const int ty = threadIdx.x >> 5;
    const int row0 = blockIdx.x * 32;

    {
        const float4* A4 = (const float4*)A;
        float4* s4 = (float4*)&a[0][0];
#pragma unroll
        for (int i = 0; i < 4; ++i) {
            int idx = threadIdx.x + i * 256;
            int r = idx >> 5, c = idx & 31;
            float4 v = make_float4(0.f, 0.f, 0.f, 0.f);
            if (row0 + r < n) v = A4[(size_t)(row0 + r) * 32 + c];
            s4[idx] = v;
        }
    }
    __syncthreads();

    float acc[4][4] = {};
    const float* wp = W + tx * 4;

#pragma unroll 2
    for (int k = 0; k < HID; k += 4) {
        float ar[4][4];
#pragma unroll
        for (int r = 0; r < 4; ++r)
            *(float4*)&ar[r][0] = *(const float4*)&a[ty * 4 + r][k];
#pragma unroll
        for (int kk = 0; kk < 4; ++kk) {
            float4 w = *(const float4*)(wp + (size_t)(k + kk) * HID);
#pragma unroll
            for (int r = 0; r < 4; ++r) {
                acc[r][0] += ar[r][kk] * w.x;
                acc[r][1] += ar[r][kk] * w.y;
                acc[r][2] += ar[r][kk] * w.z;
                acc[r][3] += ar[r][kk] * w.w;
            }
        }
    }

#pragma unroll
    for (int r = 0; r < 4; ++r) {
        int row = row0 + ty * 4 + r;
        if (row < n) {
            float d = dinv[row];
            uint2 v;
            v.x = (uint32_t)f32_to_bf16(acc[r][0] * d) | ((uint32_t)f32_to_bf16(acc[r][1] * d) << 16);
            v.y = (uint32_t)f32_to_bf16(acc[r][2] * d) | ((uint32_t)f32_to_bf16(acc[r][3] * d) << 16);
            *(uint2*)((uint16_t*)outh + (size_t)row * HID + tx * 4) = v;
        }
    }
}

// ---------------- aggregation: one wave per node, bf16 h' gather, 4-deep ----------------
// out[i] = relu( dinv[i] * sum_{j in N(i)} h'[j] + b ) [+ skip[i]]

__global__ void gnn_aggregate_k(const uint32_t* __restrict__ h, const int* __restrict__ rowptr,
                                const int* __restrict__ colidx, const float* __restrict__ dinv,
                                const float* __restrict__ bias, const float* __restrict__ skip,
                                float* __restrict__ out, int n) {
    int node = blockIdx.x * 4 + (threadIdx.x >> 6);
    if (node >= n) return;
    int lane = threadIdx.x & 63;
    int c0 = lane * 2;
    int beg = rowptr[node];
    int end = rowptr[node + 1];
    float acc0 = 0.0f, acc1 = 0.0f;
    int e = beg;
    for (; e + 3 < end; e += 4) {
        int j0 = colidx[e], j1 = colidx[e + 1], j2 = colidx[e + 2], j3 = colidx[e + 3];
        uint32_t u0 = h[(size_t)j0 * 64 + lane];
        uint32_t u1 = h[(size_t)j1 * 64 + lane];
        uint32_t u2 = h[(size_t)j2 * 64 + lane];
        uint32_t u3 = h[(size_t)j3 * 64 + lane];
        acc0 += __uint_as_float(u0 << 16);  acc1 += __uint_as_float(u0 & 0xFFFF0000u);
        acc0 += __uint_as_float(u1 << 16);  acc1 += __uint_as_float(u1 & 0xFFFF0000u);
        acc0 += __uint_as_float(u2 << 16);  acc1 += __uint_as_float(u2 & 0xFFFF0000u);
        acc0 += __uint_as_float(u3 << 16);  acc1 += __uint_as_float(u3 & 0xFFFF0000u);
    }
    for (; e < end; ++e) {
        uint32_t u = h[(size_t)colidx[e] * 64 + lane];
        acc0 += __uint_as_float(u << 16);
        acc1 += __uint_as_float(u & 0xFFFF0000u);
    }
    float di = dinv[node];
    float o0 = fmaxf(di * acc0 + bias[c0], 0.0f);
    float o1 = fmaxf(di * acc1 + bias[c0 + 1], 0.0f);
    if (skip) {
        o0 += skip[(size_t)node * HID + c0];
        o1 += skip[(size_t)node * HID + c0 + 1];
    }
    out[(size_t)node * HID + c0]     = o0;
    out[(size_t)node * HID + c0 + 1] = o1;
}

// ---------------- final: sum[n,128] @ Wc[128,40] + bc -> fp32 ----------------

__global__ __launch_bounds__(320) void gnn_final_k(const float* __restrict__ sum,
                                                   const float* __restrict__ wc,
                                                   const float* __restrict__ bc,
                                                   float* __restrict__ out, int n) {
    __shared__ float a[64 * HID];  // 32 KB, float4 block (r, c4) at r*32 + (c4 ^ (r&7))
    const int tx = threadIdx.x % 10;
    const int ty = threadIdx.x / 10;
    const int row0 = blockIdx.x * 64;

    {
        const float4* S4 = (const float4*)sum;
        float4* s4 = (float4*)a;
        for (int idx = threadIdx.x; idx < 64 * 32; idx += 320) {
            int r = idx >> 5, c = idx & 31;
            float4 v = make_float4(0.f, 0.f, 0.f, 0.f);
            if (row0 + r < n) v = S4[(size_t)(row0 + r) * 32 + c];
            s4[r * 32 + (c ^ (r & 7))] = v;
        }
    }
    __syncthreads();

    float acc[2][4];
    {
        float b0 = bc[tx * 4], b1 = bc[tx * 4 + 1], b2 = bc[tx * 4 + 2], b3 = bc[tx * 4 + 3];
        acc[0][0] = b0; acc[0][1] = b1; acc[0][2] = b2; acc[0][3] = b3;
        acc[1][0] = b0; acc[1][1] = b1; acc[1][2] = b2; acc[1][3] = b3;
    }
    const float* wp = wc + tx * 4;
    const float4* s4 = (const float4*)a;

#pragma unroll 2
    for (int k = 0; k < HID; k += 4) {
        int c4 = k >> 2;
        float ar[2][4];
#pragma unroll
        for (int r = 0; r < 2; ++r) {
            int row = ty * 2 + r;
            *(float4*)&ar[r][0] = s4[row * 32 + (c4 ^ (row & 7))];
        }
#pragma unroll
        for (int kk = 0; kk < 4; ++kk) {
            float4 w = *(const float4*)(wp + (size_t)(k + kk) * OUTD);
#pragma unroll
            for (int r = 0; r < 2; ++r) {
                acc[r][0] += ar[r][kk] * w.x;
                acc[r][1] += ar[r][kk] * w.y;
                acc[r][2] += ar[r][kk] * w.z;
                acc[r][3] += ar[r][kk] * w.w;
            }
        }
    }

#pragma unroll
    for (int r = 0; r < 2; ++r) {
        int row = row0 + ty * 2 + r;
        if (row < n) {
            float4 v = make_float4(acc[r][0], acc[r][1], acc[r][2], acc[r][3]);
            *(float4*)(out + (size_t)row * OUTD + tx * 4) = v;
        }
    }
}

// ---------------- launch ----------------

extern "C" void kernel_launch(void* const* d_in, const int* in_sizes, int n_in,
                              void* d_out, int out_size, void* d_ws, size_t ws_size,
                              hipStream_t stream) {
    const int N = in_sizes[0] / HID;   // 100000
    const int E = in_sizes[7] / 2;     // 1600000

    const float* x  = (const float*)d_in[0];
    const float* W1 = (const float*)d_in[1];
    const float* b1 = (const float*)d_in[2];
    const float* W2 = (const float*)d_in[3];
    const float* b2 = (const float*)d_in[4];
    const float* Wc = (const float*)d_in[5];
    const float* bc = (const float*)d_in[6];
    const int* edges = (const int*)d_in[7];
    float* out = (float*)d_out;

    // workspace carve-up (256B aligned), ~98 MB total
    char* w = (char*)d_ws;
    auto alloc = [&](size_t bytes) -> char* {
        char* p = w;
        w += (bytes + 255) & ~(size_t)255;
        return p;
    };
    uint16_t* hbuf = (uint16_t*)alloc((size_t)N * HID * 2);  // h' bf16 (both layers)
    float* bufB    = (float*)alloc((size_t)N * HID * 4);     // out1, then out1+out2
    int*   cnt     = (int*)alloc((size_t)N * 4);
    int*   gcur    = (int*)alloc((size_t)N * 4);             // fallback cursors (adjacent to cnt)
    int*   rowptr  = (int*)alloc((size_t)(N + 1) * 4);
    int*   scanbuf = (int*)alloc((size_t)N * 4);
    int*   bsum    = (int*)alloc(512 * 4);
    int*   pcur    = (int*)alloc(512 * 4);
    int*   colidx  = (int*)alloc((size_t)(E + N) * 4);
    float* dinv    = (float*)alloc((size_t)N * 4);
    int2*  pairbuf = (int2*)alloc((size_t)E * 8);

    const int nb1 = (N + 255) / 256;   // scan blocks (391)
    const int NB  = (N + 255) >> BSH;  // buckets (391)

    // cnt and gcur are adjacent allocations -> single memset
    size_t cntspan = (size_t)((char*)rowptr - (char*)cnt);
    hipMemsetAsync(cnt, 0, cntspan, stream);

    gnn_count_k<<<(E + 255) / 256, 256, 0, stream>>>(edges, cnt, E);
    gnn_scan_block_k<<<nb1, 256, 0, stream>>>(cnt, scanbuf, bsum, N);
    gnn_scan_bsum_k<<<1, 512, 0, stream>>>(bsum, nb1);
    gnn_write_rowptr_k<<<nb1, 256, 0, stream>>>(scanbuf, bsum, cnt, rowptr, pcur, dinv, N);
    gnn_bucket_scatter_k<<<(E + 255) / 256, 256, 0, stream>>>(edges, pcur, pairbuf, E);
    gnn_build_csr_k<<<NB, 256, 0, stream>>>(pairbuf, rowptr, colidx, gcur, N);

    // layer 1: h1' = bf16(dinv * (x @ W1)) ; out1 = relu(dinv * agg(h1') + b1)
    gnn_gemm128_k<<<(N + 31) / 32, 256, 0, stream>>>(x, W1, dinv, hbuf, N);
    gnn_aggregate_k<<<(N + 3) / 4, 256, 0, stream>>>((const uint32_t*)hbuf, rowptr, colidx,
                                                     dinv, b1, nullptr, bufB, N);
    // layer 2 (skip fused, in place)
    gnn_gemm128_k<<<(N + 31) / 32, 256, 0, stream>>>(bufB, W2, dinv, hbuf, N);
    gnn_aggregate_k<<<(N + 3) / 4, 256, 0, stream>>>((const uint32_t*)hbuf, rowptr, colidx,
                                                     dinv, b2, bufB, bufB, N);
    // head
    gnn_final_k<<<(N + 63) / 64, 320, 0, stream>>>(bufB, Wc, bc, out, N);
}

// Round 6
// 532.290 us; speedup vs baseline: 2.0079x; 2.0079x over previous
//
#include <hip/hip_runtime.h>
#include <stdint.h>

// GNN: 2-layer GCN + skip + classifier head. All fp32 in/out; edge_index int32.
// N=100000, E=1600000, F=H=128, OUT=40.
//
//   h'[j] = dinv[j] * (A_in @ W)[j]  -> stored BF16
//   out[i] = relu(dinv[i] * sum_{j in N(i)} h'[j] + b) (+ skip)   [aggregate]
//   final = (out1 + out2) @ Wc + bc   (fp32)
//
// CSR build = two-level counting sort. Pass 1 uses block-local LDS histograms +
// one global reservation atomic per (block,bucket): 77K global atomics instead of
// 1.6M on 391 addresses (round-5 regression: 4090-way same-address contention).

#define HID 128
#define OUTD 40
#define BSH 8                 // 256 nodes per bucket
#define BCAP 6144             // LDS colbuf entries per bucket (mean ~4350)
#define EPB 8192              // edges per scatter block
#define NBMAX 512

__device__ inline uint16_t f32_to_bf16(float f) {
    uint32_t u = __float_as_uint(f);
    uint32_t r = u + 0x7FFFu + ((u >> 16) & 1u);
    return (uint16_t)(r >> 16);
}

// ---------------- CSR build ----------------

__global__ void gnn_count_k(const int* __restrict__ edges, int* __restrict__ cnt, int E) {
    int t = blockIdx.x * 256 + threadIdx.x;
    if (t < E) atomicAdd(&cnt[edges[E + t]], 1);
}

// block-level inclusive scan of (cnt[i]+1)  (+1 = self loop)
__global__ void gnn_scan_block_k(const int* __restrict__ cnt, int* __restrict__ scanbuf,
                                 int* __restrict__ bsum, int n) {
    __shared__ int s[256];
    int i = blockIdx.x * 256 + threadIdx.x;
    int v = (i < n) ? (cnt[i] + 1) : 0;
    s[threadIdx.x] = v;
    __syncthreads();
    for (int off = 1; off < 256; off <<= 1) {
        int t = 0;
        if (threadIdx.x >= off) t = s[threadIdx.x - off];
        __syncthreads();
        if (threadIdx.x >= off) s[threadIdx.x] += t;
        __syncthreads();
    }
    if (i < n) scanbuf[i] = s[threadIdx.x];
    if (threadIdx.x == 255) bsum[blockIdx.x] = s[255];
}

__global__ void gnn_scan_bsum_k(int* __restrict__ bsum, int nb) {
    __shared__ int s[512];
    int v = (threadIdx.x < nb) ? bsum[threadIdx.x] : 0;
    s[threadIdx.x] = v;
    __syncthreads();
    for (int off = 1; off < 512; off <<= 1) {
        int t = 0;
        if (threadIdx.x >= off) t = s[threadIdx.x - off];
        __syncthreads();
        if (threadIdx.x >= off) s[threadIdx.x] += t;
        __syncthreads();
    }
    if (threadIdx.x < nb) bsum[threadIdx.x] = s[threadIdx.x];
}

// writes rowptr, per-bucket pair cursors (pcur), and dinv in one pass
__global__ void gnn_write_rowptr_k(const int* __restrict__ scanbuf, const int* __restrict__ bsum,
                                   const int* __restrict__ cnt, int* __restrict__ rowptr,
                                   int* __restrict__ pcur, float* __restrict__ dinv, int n) {
    int i = blockIdx.x * 256 + threadIdx.x;
    if (i == 0) { rowptr[0] = 0; pcur[0] = 0; }
    if (i < n) {
        int blk = i >> 8;
        int off = (blk > 0) ? bsum[blk - 1] : 0;
        int v = scanbuf[i] + off;
        rowptr[i + 1] = v;
        if (((i + 1) & 255) == 0) pcur[(i + 1) >> BSH] = v - (i + 1);  // bucket pair-start
        dinv[i] = rsqrtf((float)(cnt[i] + 1));
    }
}

// pass 1: per-block LDS histogram -> one reservation atomic per (block,bucket) ->
// write packed (dstlocal<<24 | src) into reserved slots.
__global__ __launch_bounds__(256) void gnn_bucket_scatter_k(const int* __restrict__ edges,
                                                            int* __restrict__ pcur,
                                                            uint32_t* __restrict__ pairbuf,
                                                            int E, int NB) {
    __shared__ int hist[NBMAX];
    int e0 = blockIdx.x * EPB;
    int e1 = min(E, e0 + EPB);
    for (int b = threadIdx.x; b < NB; b += 256) hist[b] = 0;
    __syncthreads();
    // phase A: local count
    for (int e = e0 + threadIdx.x; e < e1; e += 256)
        atomicAdd(&hist[edges[E + e] >> BSH], 1);
    __syncthreads();
    // phase B: reserve global ranges; hist becomes the running cursor
    for (int b = threadIdx.x; b < NB; b += 256) {
        int c = hist[b];
        hist[b] = (c > 0) ? atomicAdd(&pcur[b], c) : 0;
    }
    __syncthreads();
    // phase C: scatter into reserved slots
    for (int e = e0 + threadIdx.x; e < e1; e += 256) {
        int src = edges[e];
        int dst = edges[E + e];
        int pos = atomicAdd(&hist[dst >> BSH], 1);
        pairbuf[pos] = ((uint32_t)(dst & 255) << 24) | (uint32_t)src;
    }
}

// pass 2: one block per bucket; scatter within bucket in LDS, write colidx coalesced.
// Self-loop occupies slot 0 of each node's segment.
__global__ __launch_bounds__(256) void gnn_build_csr_k(const uint32_t* __restrict__ pairbuf,
                                                       const int* __restrict__ rowptr,
                                                       int* __restrict__ colidx,
                                                       int* __restrict__ gcur, int n) {
    __shared__ int cur[256];
    __shared__ int colbuf[BCAP];
    int b = blockIdx.x;
    int nb0 = b << BSH;
    int nb1 = min(n, nb0 + 256);
    int nn = nb1 - nb0;
    int segbeg = rowptr[nb0];
    int segend = rowptr[nb1];
    int seglen = segend - segbeg;
    int pairbeg = segbeg - nb0;
    int npairs = (segend - nb1) - pairbeg;

    if (seglen <= BCAP) {
        if (threadIdx.x < nn) {
            int node = nb0 + threadIdx.x;
            int rel = rowptr[node] - segbeg;
            colbuf[rel] = node;            // self loop
            cur[threadIdx.x] = rel + 1;
        }
        __syncthreads();
        for (int p = threadIdx.x; p < npairs; p += 256) {
            uint32_t pr = pairbuf[pairbeg + p];
            int pos = atomicAdd(&cur[pr >> 24], 1);
            colbuf[pos] = (int)(pr & 0xFFFFFFu);
        }
        __syncthreads();
        for (int i = threadIdx.x; i < seglen; i += 256)
            colidx[segbeg + i] = colbuf[i];
    } else {
        // overflow fallback (statistically never taken): global scatter, gcur pre-zeroed
        if (threadIdx.x < nn) {
            int node = nb0 + threadIdx.x;
            colidx[rowptr[node]] = node;
        }
        __syncthreads();
        for (int p = threadIdx.x; p < npairs; p += 256) {
            uint32_t pr = pairbuf[pairbeg + p];
            int dst = nb0 + (int)(pr >> 24);
            int pos = atomicAdd(&gcur[dst], 1);
            colidx[rowptr[dst] + 1 + pos] = (int)(pr & 0xFFFFFFu);
        }
    }
}

// ---------------- GEMM [n,128] @ [128,128], row-scaled by dinv -> bf16 h' ----------------
// 32 rows x 128 cols per block; 256 threads; each thread 4 rows x 4 cols.

__global__ __launch_bounds__(256) void gnn_gemm128_k(const float* __restrict__ A,
                                                     const float* __restrict__ W,
                                                     const float* __restrict__ dinv,
                                                     uint16_t* __restrict__ outh, int n) {
    __shared__ float a[32][HID];  // 16 KB
    const int tx = threadIdx.x & 31;
    const int ty = threadIdx.x >> 5;
    const int row0 = blockIdx.x * 32;

    {
        const float4* A4 = (const float4*)A;
        float4* s4 = (float4*)&a[0][0];
#pragma unroll
        for (int i = 0; i < 4; ++i) {
            int idx = threadIdx.x + i * 256;
            int r = idx >> 5, c = idx & 31;
            float4 v = make_float4(0.f, 0.f, 0.f, 0.f);
            if (row0 + r < n) v = A4[(size_t)(row0 + r) * 32 + c];
            s4[idx] = v;
        }
    }
    __syncthreads();

    float acc[4][4] = {};
    const float* wp = W + tx * 4;

#pragma unroll 2
    for (int k = 0; k < HID; k += 4) {
        float ar[4][4];
#pragma unroll
        for (int r = 0; r < 4; ++r)
            *(float4*)&ar[r][0] = *(const float4*)&a[ty * 4 + r][k];
#pragma unroll
        for (int kk = 0; kk < 4; ++kk) {
            float4 w = *(const float4*)(wp + (size_t)(k + kk) * HID);
#pragma unroll
            for (int r = 0; r < 4; ++r) {
                acc[r][0] += ar[r][kk] * w.x;
                acc[r][1] += ar[r][kk] * w.y;
                acc[r][2] += ar[r][kk] * w.z;
                acc[r][3] += ar[r][kk] * w.w;
            }
        }
    }

#pragma unroll
    for (int r = 0; r < 4; ++r) {
        int row = row0 + ty * 4 + r;
        if (row < n) {
            float d = dinv[row];
            uint2 v;
            v.x = (uint32_t)f32_to_bf16(acc[r][0] * d) | ((uint32_t)f32_to_bf16(acc[r][1] * d) << 16);
            v.y = (uint32_t)f32_to_bf16(acc[r][2] * d) | ((uint32_t)f32_to_bf16(acc[r][3] * d) << 16);
            *(uint2*)((uint16_t*)outh + (size_t)row * HID + tx * 4) = v;
        }
    }
}

// ---------------- aggregation: one wave per node, bf16 h' gather, 8-deep ----------------
// out[i] = relu( dinv[i] * sum_{j in N(i)} h'[j] + b ) [+ skip[i]]

__global__ void gnn_aggregate_k(const uint32_t* __restrict__ h, const int* __restrict__ rowptr,
                                const int* __restrict__ colidx, const float* __restrict__ dinv,
                                const float* __restrict__ bias, const float* __restrict__ skip,
                                float* __restrict__ out, int n) {
    int node = blockIdx.x * 4 + (threadIdx.x >> 6);
    if (node >= n) return;
    int lane = threadIdx.x & 63;
    int c0 = lane * 2;
    int beg = rowptr[node];
    int end = rowptr[node + 1];
    float acc0 = 0.0f, acc1 = 0.0f;
    int e = beg;
    for (; e + 7 < end; e += 8) {
        uint32_t u0 = h[(size_t)colidx[e]     * 64 + lane];
        uint32_t u1 = h[(size_t)colidx[e + 1] * 64 + lane];
        uint32_t u2 = h[(size_t)colidx[e + 2] * 64 + lane];
        uint32_t u3 = h[(size_t)colidx[e + 3] * 64 + lane];
        uint32_t u4 = h[(size_t)colidx[e + 4] * 64 + lane];
        uint32_t u5 = h[(size_t)colidx[e + 5] * 64 + lane];
        uint32_t u6 = h[(size_t)colidx[e + 6] * 64 + lane];
        uint32_t u7 = h[(size_t)colidx[e + 7] * 64 + lane];
        acc0 += __uint_as_float(u0 << 16);  acc1 += __uint_as_float(u0 & 0xFFFF0000u);
        acc0 += __uint_as_float(u1 << 16);  acc1 += __uint_as_float(u1 & 0xFFFF0000u);
        acc0 += __uint_as_float(u2 << 16);  acc1 += __uint_as_float(u2 & 0xFFFF0000u);
        acc0 += __uint_as_float(u3 << 16);  acc1 += __uint_as_float(u3 & 0xFFFF0000u);
        acc0 += __uint_as_float(u4 << 16);  acc1 += __uint_as_float(u4 & 0xFFFF0000u);
        acc0 += __uint_as_float(u5 << 16);  acc1 += __uint_as_float(u5 & 0xFFFF0000u);
        acc0 += __uint_as_float(u6 << 16);  acc1 += __uint_as_float(u6 & 0xFFFF0000u);
        acc0 += __uint_as_float(u7 << 16);  acc1 += __uint_as_float(u7 & 0xFFFF0000u);
    }
    for (; e < end; ++e) {
        uint32_t u = h[(size_t)colidx[e] * 64 + lane];
        acc0 += __uint_as_float(u << 16);
        acc1 += __uint_as_float(u & 0xFFFF0000u);
    }
    float di = dinv[node];
    float o0 = fmaxf(di * acc0 + bias[c0], 0.0f);
    float o1 = fmaxf(di * acc1 + bias[c0 + 1], 0.0f);
    if (skip) {
        o0 += skip[(size_t)node * HID + c0];
        o1 += skip[(size_t)node * HID + c0 + 1];
    }
    out[(size_t)node * HID + c0]     = o0;
    out[(size_t)node * HID + c0 + 1] = o1;
}

// ---------------- final: sum[n,128] @ Wc[128,40] + bc -> fp32 ----------------

__global__ __launch_bounds__(320) void gnn_final_k(const float* __restrict__ sum,
                                                   const float* __restrict__ wc,
                                                   const float* __restrict__ bc,
                                                   float* __restrict__ out, int n) {
    __shared__ float a[64 * HID];  // 32 KB, float4 block (r, c4) at r*32 + (c4 ^ (r&7))
    const int tx = threadIdx.x % 10;
    const int ty = threadIdx.x / 10;
    const int row0 = blockIdx.x * 64;

    {
        const float4* S4 = (const float4*)sum;
        float4* s4 = (float4*)a;
        for (int idx = threadIdx.x; idx < 64 * 32; idx += 320) {
            int r = idx >> 5, c = idx & 31;
            float4 v = make_float4(0.f, 0.f, 0.f, 0.f);
            if (row0 + r < n) v = S4[(size_t)(row0 + r) * 32 + c];
            s4[r * 32 + (c ^ (r & 7))] = v;
        }
    }
    __syncthreads();

    float acc[2][4];
    {
        float b0 = bc[tx * 4], b1 = bc[tx * 4 + 1], b2 = bc[tx * 4 + 2], b3 = bc[tx * 4 + 3];
        acc[0][0] = b0; acc[0][1] = b1; acc[0][2] = b2; acc[0][3] = b3;
        acc[1][0] = b0; acc[1][1] = b1; acc[1][2] = b2; acc[1][3] = b3;
    }
    const float* wp = wc + tx * 4;
    const float4* s4 = (const float4*)a;

#pragma unroll 2
    for (int k = 0; k < HID; k += 4) {
        int c4 = k >> 2;
        float ar[2][4];
#pragma unroll
        for (int r = 0; r < 2; ++r) {
            int row = ty * 2 + r;
            *(float4*)&ar[r][0] = s4[row * 32 + (c4 ^ (row & 7))];
        }
#pragma unroll
        for (int kk = 0; kk < 4; ++kk) {
            float4 w = *(const float4*)(wp + (size_t)(k + kk) * OUTD);
#pragma unroll
            for (int r = 0; r < 2; ++r) {
                acc[r][0] += ar[r][kk] * w.x;
                acc[r][1] += ar[r][kk] * w.y;
                acc[r][2] += ar[r][kk] * w.z;
                acc[r][3] += ar[r][kk] * w.w;
            }
        }
    }

#pragma unroll
    for (int r = 0; r < 2; ++r) {
        int row = row0 + ty * 2 + r;
        if (row < n) {
            float4 v = make_float4(acc[r][0], acc[r][1], acc[r][2], acc[r][3]);
            *(float4*)(out + (size_t)row * OUTD + tx * 4) = v;
        }
    }
}

// ---------------- launch ----------------

extern "C" void kernel_launch(void* const* d_in, const int* in_sizes, int n_in,
                              void* d_out, int out_size, void* d_ws, size_t ws_size,
                              hipStream_t stream) {
    const int N = in_sizes[0] / HID;   // 100000
    const int E = in_sizes[7] / 2;     // 1600000

    const float* x  = (const float*)d_in[0];
    const float* W1 = (const float*)d_in[1];
    const float* b1 = (const float*)d_in[2];
    const float* W2 = (const float*)d_in[3];
    const float* b2 = (const float*)d_in[4];
    const float* Wc = (const float*)d_in[5];
    const float* bc = (const float*)d_in[6];
    const int* edges = (const int*)d_in[7];
    float* out = (float*)d_out;

    // workspace carve-up (256B aligned)
    char* w = (char*)d_ws;
    auto alloc = [&](size_t bytes) -> char* {
        char* p = w;
        w += (bytes + 255) & ~(size_t)255;
        return p;
    };
    uint16_t* hbuf = (uint16_t*)alloc((size_t)N * HID * 2);  // h' bf16 (both layers)
    float* bufB    = (float*)alloc((size_t)N * HID * 4);     // out1, then out1+out2
    int*   cnt     = (int*)alloc((size_t)N * 4);
    int*   gcur    = (int*)alloc((size_t)N * 4);             // fallback cursors (adjacent to cnt)
    int*   rowptr  = (int*)alloc((size_t)(N + 1) * 4);
    int*   scanbuf = (int*)alloc((size_t)N * 4);
    int*   bsum    = (int*)alloc(512 * 4);
    int*   pcur    = (int*)alloc(512 * 4);
    int*   colidx  = (int*)alloc((size_t)(E + N) * 4);
    float* dinv    = (float*)alloc((size_t)N * 4);
    uint32_t* pairbuf = (uint32_t*)alloc((size_t)E * 4);

    const int nb1 = (N + 255) / 256;   // scan blocks (391)
    const int NB  = (N + 255) >> BSH;  // buckets (391)

    // cnt and gcur are adjacent allocations -> single memset
    size_t cntspan = (size_t)((char*)rowptr - (char*)cnt);
    hipMemsetAsync(cnt, 0, cntspan, stream);

    gnn_count_k<<<(E + 255) / 256, 256, 0, stream>>>(edges, cnt, E);
    gnn_scan_block_k<<<nb1, 256, 0, stream>>>(cnt, scanbuf, bsum, N);
    gnn_scan_bsum_k<<<1, 512, 0, stream>>>(bsum, nb1);
    gnn_write_rowptr_k<<<nb1, 256, 0, stream>>>(scanbuf, bsum, cnt, rowptr, pcur, dinv, N);
    gnn_bucket_scatter_k<<<(E + EPB - 1) / EPB, 256, 0, stream>>>(edges, pcur, pairbuf, E, NB);
    gnn_build_csr_k<<<NB, 256, 0, stream>>>(pairbuf, rowptr, colidx, gcur, N);

    // layer 1: h1' = bf16(dinv * (x @ W1)) ; out1 = relu(dinv * agg(h1') + b1)
    gnn_gemm128_k<<<(N + 31) / 32, 256, 0, stream>>>(x, W1, dinv, hbuf, N);
    gnn_aggregate_k<<<(N + 3) / 4, 256, 0, stream>>>((const uint32_t*)hbuf, rowptr, colidx,
                                                     dinv, b1, nullptr, bufB, N);
    // layer 2 (skip fused, in place)
    gnn_gemm128_k<<<(N + 31) / 32, 256, 0, stream>>>(bufB, W2, dinv, hbuf, N);
    gnn_aggregate_k<<<(N + 3) / 4, 256, 0, stream>>>((const uint32_t*)hbuf, rowptr, colidx,
                                                     dinv, b2, bufB, bufB, N);
    // head
    gnn_final_k<<<(N + 63) / 64, 320, 0, stream>>>(bufB, Wc, bc, out, N);
}

// Round 7
// 516.348 us; speedup vs baseline: 2.0699x; 1.0309x over previous
//
#include <hip/hip_runtime.h>
#include <stdint.h>

// GNN: 2-layer GCN + skip + classifier head. All fp32 in/out; edge_index int32.
// N=100000, E=1600000, F=H=128, OUT=40.
//
//   h'[j] = dinv[j] * (A_in @ W)[j]  -> stored BF16
//   out[i] = relu(dinv[i] * sum_{j in N(i)} h'[j] + b) (+ skip)   [aggregate]
//   final = (out1 + out2) @ Wc + bc   (fp32)
//
// CSR build = two-level counting sort (histogram-reserved scatter, round 6: 532us).
// Aggregate: 4 edge-groups x 16 lanes x dwordx4 loads (round 6 had VGPR=20 ->
// serialized dword loads; this packs 4x fewer, 4x wider loads + xor-butterfly).

#define HID 128
#define OUTD 40
#define BSH 8                 // 256 nodes per bucket
#define BCAP 6144             // LDS colbuf entries per bucket (mean ~4350)
#define EPB 8192              // edges per scatter block
#define NBMAX 512

__device__ inline uint16_t f32_to_bf16(float f) {
    uint32_t u = __float_as_uint(f);
    uint32_t r = u + 0x7FFFu + ((u >> 16) & 1u);
    return (uint16_t)(r >> 16);
}
__device__ inline float bf_lo(uint32_t u) { return __uint_as_float(u << 16); }
__device__ inline float bf_hi(uint32_t u) { return __uint_as_float(u & 0xFFFF0000u); }

// ---------------- CSR build ----------------

__global__ void gnn_count_k(const int* __restrict__ edges, int* __restrict__ cnt, int E) {
    int t = blockIdx.x * 256 + threadIdx.x;
    if (t < E) atomicAdd(&cnt[edges[E + t]], 1);
}

// block-level inclusive scan of (cnt[i]+1)  (+1 = self loop)
__global__ void gnn_scan_block_k(const int* __restrict__ cnt, int* __restrict__ scanbuf,
                                 int* __restrict__ bsum, int n) {
    __shared__ int s[256];
    int i = blockIdx.x * 256 + threadIdx.x;
    int v = (i < n) ? (cnt[i] + 1) : 0;
    s[threadIdx.x] = v;
    __syncthreads();
    for (int off = 1; off < 256; off <<= 1) {
        int t = 0;
        if (threadIdx.x >= off) t = s[threadIdx.x - off];
        __syncthreads();
        if (threadIdx.x >= off) s[threadIdx.x] += t;
        __syncthreads();
    }
    if (i < n) scanbuf[i] = s[threadIdx.x];
    if (threadIdx.x == 255) bsum[blockIdx.x] = s[255];
}

__global__ void gnn_scan_bsum_k(int* __restrict__ bsum, int nb) {
    __shared__ int s[512];
    int v = (threadIdx.x < nb) ? bsum[threadIdx.x] : 0;
    s[threadIdx.x] = v;
    __syncthreads();
    for (int off = 1; off < 512; off <<= 1) {
        int t = 0;
        if (threadIdx.x >= off) t = s[threadIdx.x - off];
        __syncthreads();
        if (threadIdx.x >= off) s[threadIdx.x] += t;
        __syncthreads();
    }
    if (threadIdx.x < nb) bsum[threadIdx.x] = s[threadIdx.x];
}

// writes rowptr, per-bucket pair cursors (pcur), and dinv in one pass
__global__ void gnn_write_rowptr_k(const int* __restrict__ scanbuf, const int* __restrict__ bsum,
                                   const int* __restrict__ cnt, int* __restrict__ rowptr,
                                   int* __restrict__ pcur, float* __restrict__ dinv, int n) {
    int i = blockIdx.x * 256 + threadIdx.x;
    if (i == 0) { rowptr[0] = 0; pcur[0] = 0; }
    if (i < n) {
        int blk = i >> 8;
        int off = (blk > 0) ? bsum[blk - 1] : 0;
        int v = scanbuf[i] + off;
        rowptr[i + 1] = v;
        if (((i + 1) & 255) == 0) pcur[(i + 1) >> BSH] = v - (i + 1);  // bucket pair-start
        dinv[i] = rsqrtf((float)(cnt[i] + 1));
    }
}

// pass 1: per-block LDS histogram -> one reservation atomic per (block,bucket) ->
// write packed (dstlocal<<24 | src) into reserved slots.
__global__ __launch_bounds__(256) void gnn_bucket_scatter_k(const int* __restrict__ edges,
                                                            int* __restrict__ pcur,
                                                            uint32_t* __restrict__ pairbuf,
                                                            int E, int NB) {
    __shared__ int hist[NBMAX];
    int e0 = blockIdx.x * EPB;
    int e1 = min(E, e0 + EPB);
    for (int b = threadIdx.x; b < NB; b += 256) hist[b] = 0;
    __syncthreads();
    for (int e = e0 + threadIdx.x; e < e1; e += 256)
        atomicAdd(&hist[edges[E + e] >> BSH], 1);
    __syncthreads();
    for (int b = threadIdx.x; b < NB; b += 256) {
        int c = hist[b];
        hist[b] = (c > 0) ? atomicAdd(&pcur[b], c) : 0;
    }
    __syncthreads();
    for (int e = e0 + threadIdx.x; e < e1; e += 256) {
        int src = edges[e];
        int dst = edges[E + e];
        int pos = atomicAdd(&hist[dst >> BSH], 1);
        pairbuf[pos] = ((uint32_t)(dst & 255) << 24) | (uint32_t)src;
    }
}

// pass 2: one block per bucket; scatter within bucket in LDS, write colidx coalesced.
__global__ __launch_bounds__(256) void gnn_build_csr_k(const uint32_t* __restrict__ pairbuf,
                                                       const int* __restrict__ rowptr,
                                                       int* __restrict__ colidx,
                                                       int* __restrict__ gcur, int n) {
    __shared__ int cur[256];
    __shared__ int colbuf[BCAP];
    int b = blockIdx.x;
    int nb0 = b << BSH;
    int nb1 = min(n, nb0 + 256);
    int nn = nb1 - nb0;
    int segbeg = rowptr[nb0];
    int segend = rowptr[nb1];
    int seglen = segend - segbeg;
    int pairbeg = segbeg - nb0;
    int npairs = (segend - nb1) - pairbeg;

    if (seglen <= BCAP) {
        if (threadIdx.x < nn) {
            int node = nb0 + threadIdx.x;
            int rel = rowptr[node] - segbeg;
            colbuf[rel] = node;            // self loop
            cur[threadIdx.x] = rel + 1;
        }
        __syncthreads();
        for (int p = threadIdx.x; p < npairs; p += 256) {
            uint32_t pr = pairbuf[pairbeg + p];
            int pos = atomicAdd(&cur[pr >> 24], 1);
            colbuf[pos] = (int)(pr & 0xFFFFFFu);
        }
        __syncthreads();
        for (int i = threadIdx.x; i < seglen; i += 256)
            colidx[segbeg + i] = colbuf[i];
    } else {
        // overflow fallback (statistically never taken): global scatter, gcur pre-zeroed
        if (threadIdx.x < nn) {
            int node = nb0 + threadIdx.x;
            colidx[rowptr[node]] = node;
        }
        __syncthreads();
        for (int p = threadIdx.x; p < npairs; p += 256) {
            uint32_t pr = pairbuf[pairbeg + p];
            int dst = nb0 + (int)(pr >> 24);
            int pos = atomicAdd(&gcur[dst], 1);
            colidx[rowptr[dst] + 1 + pos] = (int)(pr & 0xFFFFFFu);
        }
    }
}

// ---------------- GEMM [n,128] @ [128,128], row-scaled by dinv -> bf16 h' ----------------

__global__ __launch_bounds__(256) void gnn_gemm128_k(const float* __restrict__ A,
                                                     const float* __restrict__ W,
                                                     const float* __restrict__ dinv,
                                                     uint16_t* __restrict__ outh, int n) {
    __shared__ float a[32][HID];  // 16 KB
    const int tx = threadIdx.x & 31;
    const int ty = threadIdx.x >> 5;
    const int row0 = blockIdx.x * 32;

    {
        const float4* A4 = (const float4*)A;
        float4* s4 = (float4*)&a[0][0];
#pragma unroll
        for (int i = 0; i < 4; ++i) {
            int idx = threadIdx.x + i * 256;
            int r = idx >> 5, c = idx & 31;
            float4 v = make_float4(0.f, 0.f, 0.f, 0.f);
            if (row0 + r < n) v = A4[(size_t)(row0 + r) * 32 + c];
            s4[idx] = v;
        }
    }
    __syncthreads();

    float acc[4][4] = {};
    const float* wp = W + tx * 4;

#pragma unroll 2
    for (int k = 0; k < HID; k += 4) {
        float ar[4][4];
#pragma unroll
        for (int r = 0; r < 4; ++r)
            *(float4*)&ar[r][0] = *(const float4*)&a[ty * 4 + r][k];
#pragma unroll
        for (int kk = 0; kk < 4; ++kk) {
            float4 w = *(const float4*)(wp + (size_t)(k + kk) * HID);
#pragma unroll
            for (int r = 0; r < 4; ++r) {
                acc[r][0] += ar[r][kk] * w.x;
                acc[r][1] += ar[r][kk] * w.y;
                acc[r][2] += ar[r][kk] * w.z;
                acc[r][3] += ar[r][kk] * w.w;
            }
        }
    }

#pragma unroll
    for (int r = 0; r < 4; ++r) {
        int row = row0 + ty * 4 + r;
        if (row < n) {
            float d = dinv[row];
            uint2 v;
            v.x = (uint32_t)f32_to_bf16(acc[r][0] * d) | ((uint32_t)f32_to_bf16(acc[r][1] * d) << 16);
            v.y = (uint32_t)f32_to_bf16(acc[r][2] * d) | ((uint32_t)f32_to_bf16(acc[r][3] * d) << 16);
            *(uint2*)((uint16_t*)outh + (size_t)row * HID + tx * 4) = v;
        }
    }
}

// ---------------- aggregation: one wave per node, grouped dwordx4 gather ----------------
// 64 lanes = 4 edge-groups x 16 lanes. Group g handles edge e+g; lane loads uint4
// (16 B = 8 bf16 cols). Each lane accumulates 8 cols; xor-butterfly (16,32) reduces
// across groups; lanes 0..31 store float4 epilogue.

__global__ __launch_bounds__(256) void gnn_aggregate_k(const uint4* __restrict__ h4,
                                const int* __restrict__ rowptr,
                                const int* __restrict__ colidx, const float* __restrict__ dinv,
                                const float* __restrict__ bias, const float* __restrict__ skip,
                                float* __restrict__ out, int n) {
    int node = blockIdx.x * 4 + (threadIdx.x >> 6);
    if (node >= n) return;
    int lane = threadIdx.x & 63;
    int g = lane >> 4;        // edge group 0..3
    int sub = lane & 15;      // uint4 within row -> cols sub*8 .. sub*8+7
    int beg = rowptr[node];
    int end = rowptr[node + 1];
    float acc[8] = {};
    int e = beg;
    // 16 edges per iteration: 4 independent dwordx4 loads in flight per lane
    for (; e + 15 < end; e += 16) {
        int j0 = colidx[e + g];
        int j1 = colidx[e + 4 + g];
        int j2 = colidx[e + 8 + g];
        int j3 = colidx[e + 12 + g];
        uint4 u0 = h4[(size_t)j0 * 16 + sub];
        uint4 u1 = h4[(size_t)j1 * 16 + sub];
        uint4 u2 = h4[(size_t)j2 * 16 + sub];
        uint4 u3 = h4[(size_t)j3 * 16 + sub];
        acc[0] += bf_lo(u0.x); acc[1] += bf_hi(u0.x); acc[2] += bf_lo(u0.y); acc[3] += bf_hi(u0.y);
        acc[4] += bf_lo(u0.z); acc[5] += bf_hi(u0.z); acc[6] += bf_lo(u0.w); acc[7] += bf_hi(u0.w);
        acc[0] += bf_lo(u1.x); acc[1] += bf_hi(u1.x); acc[2] += bf_lo(u1.y); acc[3] += bf_hi(u1.y);
        acc[4] += bf_lo(u1.z); acc[5] += bf_hi(u1.z); acc[6] += bf_lo(u1.w); acc[7] += bf_hi(u1.w);
        acc[0] += bf_lo(u2.x); acc[1] += bf_hi(u2.x); acc[2] += bf_lo(u2.y); acc[3] += bf_hi(u2.y);
        acc[4] += bf_lo(u2.z); acc[5] += bf_hi(u2.z); acc[6] += bf_lo(u2.w); acc[7] += bf_hi(u2.w);
        acc[0] += bf_lo(u3.x); acc[1] += bf_hi(u3.x); acc[2] += bf_lo(u3.y); acc[3] += bf_hi(u3.y);
        acc[4] += bf_lo(u3.z); acc[5] += bf_hi(u3.z); acc[6] += bf_lo(u3.w); acc[7] += bf_hi(u3.w);
    }
    // 4 edges per iteration
    for (; e + 3 < end; e += 4) {
        int j = colidx[e + g];
        uint4 u = h4[(size_t)j * 16 + sub];
        acc[0] += bf_lo(u.x); acc[1] += bf_hi(u.x); acc[2] += bf_lo(u.y); acc[3] += bf_hi(u.y);
        acc[4] += bf_lo(u.z); acc[5] += bf_hi(u.z); acc[6] += bf_lo(u.w); acc[7] += bf_hi(u.w);
    }
    // tail (<4 edges): group g takes edge e+g if in range
    if (g < end - e) {
        int j = colidx[e + g];
        uint4 u = h4[(size_t)j * 16 + sub];
        acc[0] += bf_lo(u.x); acc[1] += bf_hi(u.x); acc[2] += bf_lo(u.y); acc[3] += bf_hi(u.y);
        acc[4] += bf_lo(u.z); acc[5] += bf_hi(u.z); acc[6] += bf_lo(u.w); acc[7] += bf_hi(u.w);
    }
    // reduce across the 4 groups
#pragma unroll
    for (int k = 0; k < 8; ++k) {
        acc[k] += __shfl_xor(acc[k], 16, 64);
        acc[k] += __shfl_xor(acc[k], 32, 64);
    }
    // epilogue: lanes 0..31 write float4 each (half = lane>>4, cols sub*8+half*4 ..+3)
    if (lane < 32) {
        int half = lane >> 4;
        int col = sub * 8 + half * 4;
        float di = dinv[node];
        float4 bv = *(const float4*)(bias + col);
        float o0 = fmaxf(di * acc[half * 4 + 0] + bv.x, 0.0f);
        float o1 = fmaxf(di * acc[half * 4 + 1] + bv.y, 0.0f);
        float o2 = fmaxf(di * acc[half * 4 + 2] + bv.z, 0.0f);
        float o3 = fmaxf(di * acc[half * 4 + 3] + bv.w, 0.0f);
        if (skip) {
            float4 sv = *(const float4*)(skip + (size_t)node * HID + col);
            o0 += sv.x; o1 += sv.y; o2 += sv.z; o3 += sv.w;
        }
        *(float4*)(out + (size_t)node * HID + col) = make_float4(o0, o1, o2, o3);
    }
}

// ---------------- final: sum[n,128] @ Wc[128,40] + bc -> fp32 ----------------

__global__ __launch_bounds__(320) void gnn_final_k(const float* __restrict__ sum,
                                                   const float* __restrict__ wc,
                                                   const float* __restrict__ bc,
                                                   float* __restrict__ out, int n) {
    __shared__ float a[64 * HID];  // 32 KB, float4 block (r, c4) at r*32 + (c4 ^ (r&7))
    const int tx = threadIdx.x % 10;
    const int ty = threadIdx.x / 10;
    const int row0 = blockIdx.x * 64;

    {
        const float4* S4 = (const float4*)sum;
        float4* s4 = (float4*)a;
        for (int idx = threadIdx.x; idx < 64 * 32; idx += 320) {
            int r = idx >> 5, c = idx & 31;
            float4 v = make_float4(0.f, 0.f, 0.f, 0.f);
            if (row0 + r < n) v = S4[(size_t)(row0 + r) * 32 + c];
            s4[r * 32 + (c ^ (r & 7))] = v;
        }
    }
    __syncthreads();

    float acc[2][4];
    {
        float b0 = bc[tx * 4], b1 = bc[tx * 4 + 1], b2 = bc[tx * 4 + 2], b3 = bc[tx * 4 + 3];
        acc[0][0] = b0; acc[0][1] = b1; acc[0][2] = b2; acc[0][3] = b3;
        acc[1][0] = b0; acc[1][1] = b1; acc[1][2] = b2; acc[1][3] = b3;
    }
    const float* wp = wc + tx * 4;
    const float4* s4 = (const float4*)a;

#pragma unroll 2
    for (int k = 0; k < HID; k += 4) {
        int c4 = k >> 2;
        float ar[2][4];
#pragma unroll
        for (int r = 0; r < 2; ++r) {
            int row = ty * 2 + r;
            *(float4*)&ar[r][0] = s4[row * 32 + (c4 ^ (row & 7))];
        }
#pragma unroll
        for (int kk = 0; kk < 4; ++kk) {
            float4 w = *(const float4*)(wp + (size_t)(k + kk) * OUTD);
#pragma unroll
            for (int r = 0; r < 2; ++r) {
                acc[r][0] += ar[r][kk] * w.x;
                acc[r][1] += ar[r][kk] * w.y;
                acc[r][2] += ar[r][kk] * w.z;
                acc[r][3] += ar[r][kk] * w.w;
            }
        }
    }

#pragma unroll
    for (int r = 0; r < 2; ++r) {
        int row = row0 + ty * 2 + r;
        if (row < n) {
            float4 v = make_float4(acc[r][0], acc[r][1], acc[r][2], acc[r][3]);
            *(float4*)(out + (size_t)row * OUTD + tx * 4) = v;
        }
    }
}

// ---------------- launch ----------------

extern "C" void kernel_launch(void* const* d_in, const int* in_sizes, int n_in,
                              void* d_out, int out_size, void* d_ws, size_t ws_size,
                              hipStream_t stream) {
    const int N = in_sizes[0] / HID;   // 100000
    const int E = in_sizes[7] / 2;     // 1600000

    const float* x  = (const float*)d_in[0];
    const float* W1 = (const float*)d_in[1];
    const float* b1 = (const float*)d_in[2];
    const float* W2 = (const float*)d_in[3];
    const float* b2 = (const float*)d_in[4];
    const float* Wc = (const float*)d_in[5];
    const float* bc = (const float*)d_in[6];
    const int* edges = (const int*)d_in[7];
    float* out = (float*)d_out;

    // workspace carve-up (256B aligned)
    char* w = (char*)d_ws;
    auto alloc = [&](size_t bytes) -> char* {
        char* p = w;
        w += (bytes + 255) & ~(size_t)255;
        return p;
    };
    uint16_t* hbuf = (uint16_t*)alloc((size_t)N * HID * 2);  // h' bf16 (both layers)
    float* bufB    = (float*)alloc((size_t)N * HID * 4);     // out1, then out1+out2
    int*   cnt     = (int*)alloc((size_t)N * 4);
    int*   gcur    = (int*)alloc((size_t)N * 4);             // fallback cursors (adjacent to cnt)
    int*   rowptr  = (int*)alloc((size_t)(N + 1) * 4);
    int*   scanbuf = (int*)alloc((size_t)N * 4);
    int*   bsum    = (int*)alloc(512 * 4);
    int*   pcur    = (int*)alloc(512 * 4);
    int*   colidx  = (int*)alloc((size_t)(E + N) * 4);
    float* dinv    = (float*)alloc((size_t)N * 4);
    uint32_t* pairbuf = (uint32_t*)alloc((size_t)E * 4);

    const int nb1 = (N + 255) / 256;   // scan blocks (391)
    const int NB  = (N + 255) >> BSH;  // buckets (391)

    // cnt and gcur are adjacent allocations -> single memset
    size_t cntspan = (size_t)((char*)rowptr - (char*)cnt);
    hipMemsetAsync(cnt, 0, cntspan, stream);

    gnn_count_k<<<(E + 255) / 256, 256, 0, stream>>>(edges, cnt, E);
    gnn_scan_block_k<<<nb1, 256, 0, stream>>>(cnt, scanbuf, bsum, N);
    gnn_scan_bsum_k<<<1, 512, 0, stream>>>(bsum, nb1);
    gnn_write_rowptr_k<<<nb1, 256, 0, stream>>>(scanbuf, bsum, cnt, rowptr, pcur, dinv, N);
    gnn_bucket_scatter_k<<<(E + EPB - 1) / EPB, 256, 0, stream>>>(edges, pcur, pairbuf, E, NB);
    gnn_build_csr_k<<<NB, 256, 0, stream>>>(pairbuf, rowptr, colidx, gcur, N);

    // layer 1: h1' = bf16(dinv * (x @ W1)) ; out1 = relu(dinv * agg(h1') + b1)
    gnn_gemm128_k<<<(N + 31) / 32, 256, 0, stream>>>(x, W1, dinv, hbuf, N);
    gnn_aggregate_k<<<(N + 3) / 4, 256, 0, stream>>>((const uint4*)hbuf, rowptr, colidx,
                                                     dinv, b1, nullptr, bufB, N);
    // layer 2 (skip fused, in place)
    gnn_gemm128_k<<<(N + 31) / 32, 256, 0, stream>>>(bufB, W2, dinv, hbuf, N);
    gnn_aggregate_k<<<(N + 3) / 4, 256, 0, stream>>>((const uint4*)hbuf, rowptr, colidx,
                                                     dinv, b2, bufB, bufB, N);
    // head
    gnn_final_k<<<(N + 63) / 64, 320, 0, stream>>>(bufB, Wc, bc, out, N);
}

// Round 8
// 448.927 us; speedup vs baseline: 2.3808x; 1.1502x over previous
//
#include <hip/hip_runtime.h>
#include <stdint.h>

// GNN: 2-layer GCN + skip + classifier head. All fp32 in/out; edge_index int32.
// N=100000, E=1600000, F=H=128, OUT=40.
//
//   h'[j] = dinv[j] * (A_in @ W)[j]  -> bf16, via MFMA 16x16x32 bf16
//   out[i] = relu(dinv[i] * sum_{j in N(i)} h'[j] + b) (+ skip)   [aggregate]
//   final = (out1 + out2) @ Wc + bc   (fp32)
//
// CSR build = two-level counting sort (histogram-reserved scatter).
// GEMM: per wave 16 rows x 128 cols; A-frags straight from global (1 dwordx4/ks);
// W pre-swizzled to B-frag order (32 KB, L1-resident). Layer-2 A = bf16 shadow
// written by aggregate-1 epilogue.

#define HID 128
#define OUTD 40
#define BSH 8                 // 256 nodes per bucket
#define BCAP 6144             // LDS colbuf entries per bucket (mean ~4350)
#define EPB 8192              // edges per scatter block
#define NBMAX 512

typedef __attribute__((ext_vector_type(8))) short short8;
typedef __attribute__((ext_vector_type(4))) float f32x4;

__device__ inline uint16_t f32_to_bf16(float f) {
    uint32_t u = __float_as_uint(f);
    uint32_t r = u + 0x7FFFu + ((u >> 16) & 1u);
    return (uint16_t)(r >> 16);
}
__device__ inline uint32_t pack_bf16x2(float lo, float hi) {
    return (uint32_t)f32_to_bf16(lo) | ((uint32_t)f32_to_bf16(hi) << 16);
}
__device__ inline float bf_lo(uint32_t u) { return __uint_as_float(u << 16); }
__device__ inline float bf_hi(uint32_t u) { return __uint_as_float(u & 0xFFFF0000u); }

// ---------------- CSR build ----------------

__global__ void gnn_count_k(const int* __restrict__ edges, int* __restrict__ cnt, int E) {
    int t = blockIdx.x * 256 + threadIdx.x;
    if (t < E) atomicAdd(&cnt[edges[E + t]], 1);
}

__global__ void gnn_scan_block_k(const int* __restrict__ cnt, int* __restrict__ scanbuf,
                                 int* __restrict__ bsum, int n) {
    __shared__ int s[256];
    int i = blockIdx.x * 256 + threadIdx.x;
    int v = (i < n) ? (cnt[i] + 1) : 0;
    s[threadIdx.x] = v;
    __syncthreads();
    for (int off = 1; off < 256; off <<= 1) {
        int t = 0;
        if (threadIdx.x >= off) t = s[threadIdx.x - off];
        __syncthreads();
        if (threadIdx.x >= off) s[threadIdx.x] += t;
        __syncthreads();
    }
    if (i < n) scanbuf[i] = s[threadIdx.x];
    if (threadIdx.x == 255) bsum[blockIdx.x] = s[255];
}

__global__ void gnn_scan_bsum_k(int* __restrict__ bsum, int nb) {
    __shared__ int s[512];
    int v = (threadIdx.x < nb) ? bsum[threadIdx.x] : 0;
    s[threadIdx.x] = v;
    __syncthreads();
    for (int off = 1; off < 512; off <<= 1) {
        int t = 0;
        if (threadIdx.x >= off) t = s[threadIdx.x - off];
        __syncthreads();
        if (threadIdx.x >= off) s[threadIdx.x] += t;
        __syncthreads();
    }
    if (threadIdx.x < nb) bsum[threadIdx.x] = s[threadIdx.x];
}

__global__ void gnn_write_rowptr_k(const int* __restrict__ scanbuf, const int* __restrict__ bsum,
                                   const int* __restrict__ cnt, int* __restrict__ rowptr,
                                   int* __restrict__ pcur, float* __restrict__ dinv, int n) {
    int i = blockIdx.x * 256 + threadIdx.x;
    if (i == 0) { rowptr[0] = 0; pcur[0] = 0; }
    if (i < n) {
        int blk = i >> 8;
        int off = (blk > 0) ? bsum[blk - 1] : 0;
        int v = scanbuf[i] + off;
        rowptr[i + 1] = v;
        if (((i + 1) & 255) == 0) pcur[(i + 1) >> BSH] = v - (i + 1);
        dinv[i] = rsqrtf((float)(cnt[i] + 1));
    }
}

__global__ __launch_bounds__(256) void gnn_bucket_scatter_k(const int* __restrict__ edges,
                                                            int* __restrict__ pcur,
                                                            uint32_t* __restrict__ pairbuf,
                                                            int E, int NB) {
    __shared__ int hist[NBMAX];
    int e0 = blockIdx.x * EPB;
    int e1 = min(E, e0 + EPB);
    for (int b = threadIdx.x; b < NB; b += 256) hist[b] = 0;
    __syncthreads();
    for (int e = e0 + threadIdx.x; e < e1; e += 256)
        atomicAdd(&hist[edges[E + e] >> BSH], 1);
    __syncthreads();
    for (int b = threadIdx.x; b < NB; b += 256) {
        int c = hist[b];
        hist[b] = (c > 0) ? atomicAdd(&pcur[b], c) : 0;
    }
    __syncthreads();
    for (int e = e0 + threadIdx.x; e < e1; e += 256) {
        int src = edges[e];
        int dst = edges[E + e];
        int pos = atomicAdd(&hist[dst >> BSH], 1);
        pairbuf[pos] = ((uint32_t)(dst & 255) << 24) | (uint32_t)src;
    }
}

__global__ __launch_bounds__(256) void gnn_build_csr_k(const uint32_t* __restrict__ pairbuf,
                                                       const int* __restrict__ rowptr,
                                                       int* __restrict__ colidx,
                                                       int* __restrict__ gcur, int n) {
    __shared__ int cur[256];
    __shared__ int colbuf[BCAP];
    int b = blockIdx.x;
    int nb0 = b << BSH;
    int nb1 = min(n, nb0 + 256);
    int nn = nb1 - nb0;
    int segbeg = rowptr[nb0];
    int segend = rowptr[nb1];
    int seglen = segend - segbeg;
    int pairbeg = segbeg - nb0;
    int npairs = (segend - nb1) - pairbeg;

    if (seglen <= BCAP) {
        if (threadIdx.x < nn) {
            int node = nb0 + threadIdx.x;
            int rel = rowptr[node] - segbeg;
            colbuf[rel] = node;            // self loop
            cur[threadIdx.x] = rel + 1;
        }
        __syncthreads();
        for (int p = threadIdx.x; p < npairs; p += 256) {
            uint32_t pr = pairbuf[pairbeg + p];
            int pos = atomicAdd(&cur[pr >> 24], 1);
            colbuf[pos] = (int)(pr & 0xFFFFFFu);
        }
        __syncthreads();
        for (int i = threadIdx.x; i < seglen; i += 256)
            colidx[segbeg + i] = colbuf[i];
    } else {
        if (threadIdx.x < nn) {
            int node = nb0 + threadIdx.x;
            colidx[rowptr[node]] = node;
        }
        __syncthreads();
        for (int p = threadIdx.x; p < npairs; p += 256) {
            uint32_t pr = pairbuf[pairbeg + p];
            int dst = nb0 + (int)(pr >> 24);
            int pos = atomicAdd(&gcur[dst], 1);
            colidx[rowptr[dst] + 1 + pos] = (int)(pr & 0xFFFFFFu);
        }
    }
}

// ---------------- W swizzle: fp32 [128][128] -> bf16 B-fragment order ----------------
// Wsw[((ct*4+ks)*64 + lane)*8 + j] = bf16(W[(ks*32 + (lane>>4)*8 + j)*128 + ct*16 + (lane&15)])
// 16 blocks: 0..7 -> W1, 8..15 -> W2.

__global__ void gnn_wswizzle_k(const float* __restrict__ W1, const float* __restrict__ W2,
                               uint16_t* __restrict__ w1s, uint16_t* __restrict__ w2s) {
    int b = blockIdx.x;
    const float* W = (b < 8) ? W1 : W2;
    uint16_t* O = (b < 8) ? w1s : w2s;
    int t = (b & 7) * 256 + threadIdx.x;   // 0..2047
    int lane = t & 63;
    int ksct = t >> 6;                     // ct*4+ks, 0..31
    int nn = (ksct >> 2) * 16 + (lane & 15);
    int k0 = (ksct & 3) * 32 + (lane >> 4) * 8;
    uint32_t d[4];
#pragma unroll
    for (int j = 0; j < 4; ++j)
        d[j] = pack_bf16x2(W[(size_t)(k0 + 2 * j) * HID + nn],
                           W[(size_t)(k0 + 2 * j + 1) * HID + nn]);
    *(uint4*)(O + (size_t)t * 8) = make_uint4(d[0], d[1], d[2], d[3]);
}

// ---------------- MFMA GEMM [n,128] @ [128,128], row-scaled by dinv -> bf16 h' ----------------
// 256 threads = 4 waves x 16 rows. Per wave: 8 col-tiles x 4 K-steps of 16x16x32 bf16.
// A-frag (A[m=lane&15][k=quad*8+j]) loaded straight from global; ABF16 picks fp32/bf16 A.
// D layout: col=lane&15, row=quad*4+reg.

template <bool ABF16>
__global__ __launch_bounds__(256) void gnn_gemm_mfma_k(const void* __restrict__ Aptr,
                                                       const uint32_t* __restrict__ Wsw,
                                                       const float* __restrict__ dinv,
                                                       uint16_t* __restrict__ outh, int n) {
    int wave = threadIdx.x >> 6;
    int lane = threadIdx.x & 63;
    int m = lane & 15;
    int q = lane >> 4;
    int row0 = blockIdx.x * 64 + wave * 16;
    int arow = min(row0 + m, n - 1);

    f32x4 acc[8];
#pragma unroll
    for (int i = 0; i < 8; ++i) acc[i] = (f32x4){0.f, 0.f, 0.f, 0.f};

#pragma unroll
    for (int ks = 0; ks < 4; ++ks) {
        short8 a;
        if (ABF16) {
            const uint16_t* Ab = (const uint16_t*)Aptr;
            uint4 u = *(const uint4*)(Ab + (size_t)arow * HID + ks * 32 + q * 8);
            a = __builtin_bit_cast(short8, u);
        } else {
            const float* Af = (const float*)Aptr + (size_t)arow * HID + ks * 32 + q * 8;
            uint4 u0 = *(const uint4*)(Af);
            uint4 u1 = *(const uint4*)(Af + 4);
            uint4 p;
            p.x = pack_bf16x2(__uint_as_float(u0.x), __uint_as_float(u0.y));
            p.y = pack_bf16x2(__uint_as_float(u0.z), __uint_as_float(u0.w));
            p.z = pack_bf16x2(__uint_as_float(u1.x), __uint_as_float(u1.y));
            p.w = pack_bf16x2(__uint_as_float(u1.z), __uint_as_float(u1.w));
            a = __builtin_bit_cast(short8, p);
        }
#pragma unroll
        for (int ct = 0; ct < 8; ++ct) {
            uint4 bu = *(const uint4*)(Wsw + ((size_t)(ct * 4 + ks) * 64 + lane) * 4);
            short8 bfr = __builtin_bit_cast(short8, bu);
            acc[ct] = __builtin_amdgcn_mfma_f32_16x16x32_bf16(a, bfr, acc[ct], 0, 0, 0);
        }
    }

    float dv[4];
#pragma unroll
    for (int r = 0; r < 4; ++r) dv[r] = dinv[min(row0 + q * 4 + r, n - 1)];

#pragma unroll
    for (int ct = 0; ct < 8; ++ct) {
#pragma unroll
        for (int r = 0; r < 4; ++r) {
            int rr = row0 + q * 4 + r;
            if (rr < n)
                outh[(size_t)rr * HID + ct * 16 + m] = f32_to_bf16(acc[ct][r] * dv[r]);
        }
    }
}

// ---------------- aggregation: one wave per node, grouped dwordx4 gather ----------------
// 64 lanes = 4 edge-groups x 16 lanes; xor-butterfly reduce; lanes 0..31 store float4.
// Optionally writes a bf16 shadow (next layer's MFMA A input).

__global__ __launch_bounds__(256) void gnn_aggregate_k(const uint4* __restrict__ h4,
                                const int* __restrict__ rowptr,
                                const int* __restrict__ colidx, const float* __restrict__ dinv,
                                const float* __restrict__ bias, const float* __restrict__ skip,
                                float* __restrict__ out, uint16_t* __restrict__ shadow, int n) {
    int node = blockIdx.x * 4 + (threadIdx.x >> 6);
    if (node >= n) return;
    int lane = threadIdx.x & 63;
    int g = lane >> 4;
    int sub = lane & 15;
    int beg = rowptr[node];
    int end = rowptr[node + 1];
    float acc[8] = {};
    int e = beg;
    for (; e + 15 < end; e += 16) {
        int j0 = colidx[e + g];
        int j1 = colidx[e + 4 + g];
        int j2 = colidx[e + 8 + g];
        int j3 = colidx[e + 12 + g];
        uint4 u0 = h4[(size_t)j0 * 16 + sub];
        uint4 u1 = h4[(size_t)j1 * 16 + sub];
        uint4 u2 = h4[(size_t)j2 * 16 + sub];
        uint4 u3 = h4[(size_t)j3 * 16 + sub];
        acc[0] += bf_lo(u0.x); acc[1] += bf_hi(u0.x); acc[2] += bf_lo(u0.y); acc[3] += bf_hi(u0.y);
        acc[4] += bf_lo(u0.z); acc[5] += bf_hi(u0.z); acc[6] += bf_lo(u0.w); acc[7] += bf_hi(u0.w);
        acc[0] += bf_lo(u1.x); acc[1] += bf_hi(u1.x); acc[2] += bf_lo(u1.y); acc[3] += bf_hi(u1.y);
        acc[4] += bf_lo(u1.z); acc[5] += bf_hi(u1.z); acc[6] += bf_lo(u1.w); acc[7] += bf_hi(u1.w);
        acc[0] += bf_lo(u2.x); acc[1] += bf_hi(u2.x); acc[2] += bf_lo(u2.y); acc[3] += bf_hi(u2.y);
        acc[4] += bf_lo(u2.z); acc[5] += bf_hi(u2.z); acc[6] += bf_lo(u2.w); acc[7] += bf_hi(u2.w);
        acc[0] += bf_lo(u3.x); acc[1] += bf_hi(u3.x); acc[2] += bf_lo(u3.y); acc[3] += bf_hi(u3.y);
        acc[4] += bf_lo(u3.z); acc[5] += bf_hi(u3.z); acc[6] += bf_lo(u3.w); acc[7] += bf_hi(u3.w);
    }
    for (; e + 3 < end; e += 4) {
        int j = colidx[e + g];
        uint4 u = h4[(size_t)j * 16 + sub];
        acc[0] += bf_lo(u.x); acc[1] += bf_hi(u.x); acc[2] += bf_lo(u.y); acc[3] += bf_hi(u.y);
        acc[4] += bf_lo(u.z); acc[5] += bf_hi(u.z); acc[6] += bf_lo(u.w); acc[7] += bf_hi(u.w);
    }
    if (g < end - e) {
        int j = colidx[e + g];
        uint4 u = h4[(size_t)j * 16 + sub];
        acc[0] += bf_lo(u.x); acc[1] += bf_hi(u.x); acc[2] += bf_lo(u.y); acc[3] += bf_hi(u.y);
        acc[4] += bf_lo(u.z); acc[5] += bf_hi(u.z); acc[6] += bf_lo(u.w); acc[7] += bf_hi(u.w);
    }
#pragma unroll
    for (int k = 0; k < 8; ++k) {
        acc[k] += __shfl_xor(acc[k], 16, 64);
        acc[k] += __shfl_xor(acc[k], 32, 64);
    }
    if (lane < 32) {
        int half = lane >> 4;
        int col = sub * 8 + half * 4;
        float di = dinv[node];
        float4 bv = *(const float4*)(bias + col);
        float o0 = fmaxf(di * acc[half * 4 + 0] + bv.x, 0.0f);
        float o1 = fmaxf(di * acc[half * 4 + 1] + bv.y, 0.0f);
        float o2 = fmaxf(di * acc[half * 4 + 2] + bv.z, 0.0f);
        float o3 = fmaxf(di * acc[half * 4 + 3] + bv.w, 0.0f);
        if (shadow) {
            uint2 sh;
            sh.x = pack_bf16x2(o0, o1);
            sh.y = pack_bf16x2(o2, o3);
            *(uint2*)(shadow + (size_t)node * HID + col) = sh;
        }
        if (skip) {
            float4 sv = *(const float4*)(skip + (size_t)node * HID + col);
            o0 += sv.x; o1 += sv.y; o2 += sv.z; o3 += sv.w;
        }
        *(float4*)(out + (size_t)node * HID + col) = make_float4(o0, o1, o2, o3);
    }
}

// ---------------- final: sum[n,128] @ Wc[128,40] + bc -> fp32 ----------------

__global__ __launch_bounds__(320) void gnn_final_k(const float* __restrict__ sum,
                                                   const float* __restrict__ wc,
                                                   const float* __restrict__ bc,
                                                   float* __restrict__ out, int n) {
    __shared__ float a[64 * HID];  // 32 KB, float4 block (r, c4) at r*32 + (c4 ^ (r&7))
    const int tx = threadIdx.x % 10;
    const int ty = threadIdx.x / 10;
    const int row0 = blockIdx.x * 64;

    {
        const float4* S4 = (const float4*)sum;
        float4* s4 = (float4*)a;
        for (int idx = threadIdx.x; idx < 64 * 32; idx += 320) {
            int r = idx >> 5, c = idx & 31;
            float4 v = make_float4(0.f, 0.f, 0.f, 0.f);
            if (row0 + r < n) v = S4[(size_t)(row0 + r) * 32 + c];
            s4[r * 32 + (c ^ (r & 7))] = v;
        }
    }
    __syncthreads();

    float acc[2][4];
    {
        float b0 = bc[tx * 4], b1 = bc[tx * 4 + 1], b2 = bc[tx * 4 + 2], b3 = bc[tx * 4 + 3];
        acc[0][0] = b0; acc[0][1] = b1; acc[0][2] = b2; acc[0][3] = b3;
        acc[1][0] = b0; acc[1][1] = b1; acc[1][2] = b2; acc[1][3] = b3;
    }
    const float* wp = wc + tx * 4;
    const float4* s4 = (const float4*)a;

#pragma unroll 2
    for (int k = 0; k < HID; k += 4) {
        int c4 = k >> 2;
        float ar[2][4];
#pragma unroll
        for (int r = 0; r < 2; ++r) {
            int row = ty * 2 + r;
            *(float4*)&ar[r][0] = s4[row * 32 + (c4 ^ (row & 7))];
        }
#pragma unroll
        for (int kk = 0; kk < 4; ++kk) {
            float4 w = *(const float4*)(wp + (size_t)(k + kk) * OUTD);
#pragma unroll
            for (int r = 0; r < 2; ++r) {
                acc[r][0] += ar[r][kk] * w.x;
                acc[r][1] += ar[r][kk] * w.y;
                acc[r][2] += ar[r][kk] * w.z;
                acc[r][3] += ar[r][kk] * w.w;
            }
        }
    }

#pragma unroll
    for (int r = 0; r < 2; ++r) {
        int row = row0 + ty * 2 + r;
        if (row < n) {
            float4 v = make_float4(acc[r][0], acc[r][1], acc[r][2], acc[r][3]);
            *(float4*)(out + (size_t)row * OUTD + tx * 4) = v;
        }
    }
}

// ---------------- launch ----------------

extern "C" void kernel_launch(void* const* d_in, const int* in_sizes, int n_in,
                              void* d_out, int out_size, void* d_ws, size_t ws_size,
                              hipStream_t stream) {
    const int N = in_sizes[0] / HID;   // 100000
    const int E = in_sizes[7] / 2;     // 1600000

    const float* x  = (const float*)d_in[0];
    const float* W1 = (const float*)d_in[1];
    const float* b1 = (const float*)d_in[2];
    const float* W2 = (const float*)d_in[3];
    const float* b2 = (const float*)d_in[4];
    const float* Wc = (const float*)d_in[5];
    const float* bc = (const float*)d_in[6];
    const int* edges = (const int*)d_in[7];
    float* out = (float*)d_out;

    // workspace carve-up (256B aligned)
    char* w = (char*)d_ws;
    auto alloc = [&](size_t bytes) -> char* {
        char* p = w;
        w += (bytes + 255) & ~(size_t)255;
        return p;
    };
    uint16_t* hbuf  = (uint16_t*)alloc((size_t)N * HID * 2);  // h' bf16 (both layers)
    float* bufB     = (float*)alloc((size_t)N * HID * 4);     // out1, then out1+out2
    uint16_t* bufBh = (uint16_t*)alloc((size_t)N * HID * 2);  // bf16 shadow of out1
    int*   cnt     = (int*)alloc((size_t)N * 4);
    int*   gcur    = (int*)alloc((size_t)N * 4);
    int*   rowptr  = (int*)alloc((size_t)(N + 1) * 4);
    int*   scanbuf = (int*)alloc((size_t)N * 4);
    int*   bsum    = (int*)alloc(512 * 4);
    int*   pcur    = (int*)alloc(512 * 4);
    int*   colidx  = (int*)alloc((size_t)(E + N) * 4);
    float* dinv    = (float*)alloc((size_t)N * 4);
    uint32_t* pairbuf = (uint32_t*)alloc((size_t)E * 4);
    uint16_t* w1s  = (uint16_t*)alloc(HID * HID * 2);
    uint16_t* w2s  = (uint16_t*)alloc(HID * HID * 2);

    const int nb1 = (N + 255) / 256;   // scan blocks (391)
    const int NB  = (N + 255) >> BSH;  // buckets (391)

    size_t cntspan = (size_t)((char*)rowptr - (char*)cnt);
    hipMemsetAsync(cnt, 0, cntspan, stream);

    gnn_count_k<<<(E + 255) / 256, 256, 0, stream>>>(edges, cnt, E);
    gnn_scan_block_k<<<nb1, 256, 0, stream>>>(cnt, scanbuf, bsum, N);
    gnn_scan_bsum_k<<<1, 512, 0, stream>>>(bsum, nb1);
    gnn_write_rowptr_k<<<nb1, 256, 0, stream>>>(scanbuf, bsum, cnt, rowptr, pcur, dinv, N);
    gnn_bucket_scatter_k<<<(E + EPB - 1) / EPB, 256, 0, stream>>>(edges, pcur, pairbuf, E, NB);
    gnn_build_csr_k<<<NB, 256, 0, stream>>>(pairbuf, rowptr, colidx, gcur, N);
    gnn_wswizzle_k<<<16, 256, 0, stream>>>(W1, W2, w1s, w2s);

    // layer 1: h1' = bf16(dinv * (x @ W1)) ; out1 = relu(dinv * agg(h1') + b1), bf16 shadow
    gnn_gemm_mfma_k<false><<<(N + 63) / 64, 256, 0, stream>>>(x, (const uint32_t*)w1s, dinv, hbuf, N);
    gnn_aggregate_k<<<(N + 3) / 4, 256, 0, stream>>>((const uint4*)hbuf, rowptr, colidx,
                                                     dinv, b1, nullptr, bufB, bufBh, N);
    // layer 2 (skip fused, in place; A = bf16 shadow)
    gnn_gemm_mfma_k<true><<<(N + 63) / 64, 256, 0, stream>>>(bufBh, (const uint32_t*)w2s, dinv, hbuf, N);
    gnn_aggregate_k<<<(N + 3) / 4, 256, 0, stream>>>((const uint4*)hbuf, rowptr, colidx,
                                                     dinv, b2, bufB, bufB, nullptr, N);
    // head
    gnn_final_k<<<(N + 63) / 64, 320, 0, stream>>>(bufB, Wc, bc, out, N);
}

// Round 9
// 425.424 us; speedup vs baseline: 2.5123x; 1.0552x over previous
//
#include <hip/hip_runtime.h>
#include <stdint.h>

// GNN: 2-layer GCN + skip + classifier head. All fp32 in/out; edge_index int32.
// N=100000, E=1600000, F=H=128, OUT=40.
//
//   h'[j] = dinv[j] * (A_in @ W)[j]  -> bf16, via MFMA 16x16x32 bf16
//   out1 = relu(dinv * agg(h1') + b1)            -> bf16 shadow only
//   sum  = relu(dinv * agg(h2') + b2) + out1     -> bf16, in place over shadow
//   final = sum @ Wc + bc                        -> fp32
//
// CSR build = two-level counting sort (histogram-reserved scatter). All
// inter-stage tensors bf16 (halves L3/HBM traffic vs fp32). 11 launches.

#define HID 128
#define OUTD 40
#define BSH 8                 // 256 nodes per bucket
#define BCAP 6144             // LDS colbuf entries per bucket (mean ~4350)
#define EPB 8192              // edges per scatter block
#define NBMAX 512

typedef __attribute__((ext_vector_type(8))) short short8;
typedef __attribute__((ext_vector_type(4))) float f32x4;

__device__ inline uint16_t f32_to_bf16(float f) {
    uint32_t u = __float_as_uint(f);
    uint32_t r = u + 0x7FFFu + ((u >> 16) & 1u);
    return (uint16_t)(r >> 16);
}
__device__ inline uint32_t pack_bf16x2(float lo, float hi) {
    return (uint32_t)f32_to_bf16(lo) | ((uint32_t)f32_to_bf16(hi) << 16);
}
__device__ inline float bf_lo(uint32_t u) { return __uint_as_float(u << 16); }
__device__ inline float bf_hi(uint32_t u) { return __uint_as_float(u & 0xFFFF0000u); }

// ---------------- CSR build ----------------

__global__ void gnn_count_k(const int* __restrict__ edges, int* __restrict__ cnt, int E) {
    int t = blockIdx.x * 256 + threadIdx.x;
    if (t < E) atomicAdd(&cnt[edges[E + t]], 1);
}

__global__ void gnn_scan_block_k(const int* __restrict__ cnt, int* __restrict__ scanbuf,
                                 int* __restrict__ bsum, int n) {
    __shared__ int s[256];
    int i = blockIdx.x * 256 + threadIdx.x;
    int v = (i < n) ? (cnt[i] + 1) : 0;
    s[threadIdx.x] = v;
    __syncthreads();
    for (int off = 1; off < 256; off <<= 1) {
        int t = 0;
        if (threadIdx.x >= off) t = s[threadIdx.x - off];
        __syncthreads();
        if (threadIdx.x >= off) s[threadIdx.x] += t;
        __syncthreads();
    }
    if (i < n) scanbuf[i] = s[threadIdx.x];
    if (threadIdx.x == 255) bsum[blockIdx.x] = s[255];
}

// blocks [0,nbk): rowptr + pcur + dinv (bsum prefix re-reduced per block — bsum is
// 1.5 KB L2-hot, cheaper than a separate single-block scan + extra launch).
// blocks [nbk, nbk+16): W swizzle fp32 -> bf16 B-fragment order.
// Wsw[((ct*4+ks)*64+lane)*8+j] = bf16(W[(ks*32+(lane>>4)*8+j)*128 + ct*16+(lane&15)])
__global__ __launch_bounds__(256) void gnn_setup_k(const int* __restrict__ scanbuf,
                                                   const int* __restrict__ bsum,
                                                   const int* __restrict__ cnt,
                                                   int* __restrict__ rowptr,
                                                   int* __restrict__ pcur,
                                                   float* __restrict__ dinv,
                                                   const float* __restrict__ W1,
                                                   const float* __restrict__ W2,
                                                   uint16_t* __restrict__ w1s,
                                                   uint16_t* __restrict__ w2s,
                                                   int n, int nbk) {
    int b = blockIdx.x;
    if (b < nbk) {
        __shared__ int red[256];
        int t = threadIdx.x;
        int part = 0;
        for (int i = t; i < b; i += 256) part += bsum[i];
        red[t] = part;
        __syncthreads();
        for (int off = 128; off > 0; off >>= 1) {
            if (t < off) red[t] += red[t + off];
            __syncthreads();
        }
        int off0 = red[0];
        int i = b * 256 + t;
        if (i == 0) { rowptr[0] = 0; pcur[0] = 0; }
        if (i < n) {
            int v = scanbuf[i] + off0;
            rowptr[i + 1] = v;
            if (((i + 1) & 255) == 0) pcur[(i + 1) >> BSH] = v - (i + 1);
            dinv[i] = rsqrtf((float)(cnt[i] + 1));
        }
    } else {
        int wb = b - nbk;                      // 0..15
        const float* W = (wb < 8) ? W1 : W2;
        uint16_t* O = (wb < 8) ? w1s : w2s;
        int t = (wb & 7) * 256 + threadIdx.x;  // 0..2047
        int lane = t & 63;
        int ksct = t >> 6;                     // ct*4+ks
        int nn = (ksct >> 2) * 16 + (lane & 15);
        int k0 = (ksct & 3) * 32 + (lane >> 4) * 8;
        uint32_t d[4];
#pragma unroll
        for (int j = 0; j < 4; ++j)
            d[j] = pack_bf16x2(W[(size_t)(k0 + 2 * j) * HID + nn],
                               W[(size_t)(k0 + 2 * j + 1) * HID + nn]);
        *(uint4*)(O + (size_t)t * 8) = make_uint4(d[0], d[1], d[2], d[3]);
    }
}

__global__ __launch_bounds__(256) void gnn_bucket_scatter_k(const int* __restrict__ edges,
                                                            int* __restrict__ pcur,
                                                            uint32_t* __restrict__ pairbuf,
                                                            int E, int NB) {
    __shared__ int hist[NBMAX];
    int e0 = blockIdx.x * EPB;
    int e1 = min(E, e0 + EPB);
    for (int b = threadIdx.x; b < NB; b += 256) hist[b] = 0;
    __syncthreads();
    for (int e = e0 + threadIdx.x; e < e1; e += 256)
        atomicAdd(&hist[edges[E + e] >> BSH], 1);
    __syncthreads();
    for (int b = threadIdx.x; b < NB; b += 256) {
        int c = hist[b];
        hist[b] = (c > 0) ? atomicAdd(&pcur[b], c) : 0;
    }
    __syncthreads();
    for (int e = e0 + threadIdx.x; e < e1; e += 256) {
        int src = edges[e];
        int dst = edges[E + e];
        int pos = atomicAdd(&hist[dst >> BSH], 1);
        pairbuf[pos] = ((uint32_t)(dst & 255) << 24) | (uint32_t)src;
    }
}

__global__ __launch_bounds__(256) void gnn_build_csr_k(const uint32_t* __restrict__ pairbuf,
                                                       const int* __restrict__ rowptr,
                                                       int* __restrict__ colidx,
                                                       int* __restrict__ gcur, int n) {
    __shared__ int cur[256];
    __shared__ int colbuf[BCAP];
    int b = blockIdx.x;
    int nb0 = b << BSH;
    int nb1 = min(n, nb0 + 256);
    int nn = nb1 - nb0;
    int segbeg = rowptr[nb0];
    int segend = rowptr[nb1];
    int seglen = segend - segbeg;
    int pairbeg = segbeg - nb0;
    int npairs = (segend - nb1) - pairbeg;

    if (seglen <= BCAP) {
        if (threadIdx.x < nn) {
            int node = nb0 + threadIdx.x;
            int rel = rowptr[node] - segbeg;
            colbuf[rel] = node;            // self loop
            cur[threadIdx.x] = rel + 1;
        }
        __syncthreads();
        for (int p = threadIdx.x; p < npairs; p += 256) {
            uint32_t pr = pairbuf[pairbeg + p];
            int pos = atomicAdd(&cur[pr >> 24], 1);
            colbuf[pos] = (int)(pr & 0xFFFFFFu);
        }
        __syncthreads();
        for (int i = threadIdx.x; i < seglen; i += 256)
            colidx[segbeg + i] = colbuf[i];
    } else {
        if (threadIdx.x < nn) {
            int node = nb0 + threadIdx.x;
            colidx[rowptr[node]] = node;
        }
        __syncthreads();
        for (int p = threadIdx.x; p < npairs; p += 256) {
            uint32_t pr = pairbuf[pairbeg + p];
            int dst = nb0 + (int)(pr >> 24);
            int pos = atomicAdd(&gcur[dst], 1);
            colidx[rowptr[dst] + 1 + pos] = (int)(pr & 0xFFFFFFu);
        }
    }
}

// ---------------- MFMA GEMM [n,128] @ [128,128], row-scaled by dinv -> bf16 h' ----------------
// 256 threads = 4 waves x 16 rows. Per wave: 8 col-tiles x 4 K-steps of 16x16x32 bf16.
// A-frag (A[m=lane&15][k=quad*8+j]) straight from global; ABF16 picks fp32/bf16 A.
// D layout: col=lane&15, row=quad*4+reg.

template <bool ABF16>
__global__ __launch_bounds__(256) void gnn_gemm_mfma_k(const void* __restrict__ Aptr,
                                                       const uint32_t* __restrict__ Wsw,
                                                       const float* __restrict__ dinv,
                                                       uint16_t* __restrict__ outh, int n) {
    int wave = threadIdx.x >> 6;
    int lane = threadIdx.x & 63;
    int m = lane & 15;
    int q = lane >> 4;
    int row0 = blockIdx.x * 64 + wave * 16;
    int arow = min(row0 + m, n - 1);

    f32x4 acc[8];
#pragma unroll
    for (int i = 0; i < 8; ++i) acc[i] = (f32x4){0.f, 0.f, 0.f, 0.f};

#pragma unroll
    for (int ks = 0; ks < 4; ++ks) {
        short8 a;
        if (ABF16) {
            const uint16_t* Ab = (const uint16_t*)Aptr;
            uint4 u = *(const uint4*)(Ab + (size_t)arow * HID + ks * 32 + q * 8);
            a = __builtin_bit_cast(short8, u);
        } else {
            const float* Af = (const float*)Aptr + (size_t)arow * HID + ks * 32 + q * 8;
            uint4 u0 = *(const uint4*)(Af);
            uint4 u1 = *(const uint4*)(Af + 4);
            uint4 p;
            p.x = pack_bf16x2(__uint_as_float(u0.x), __uint_as_float(u0.y));
            p.y = pack_bf16x2(__uint_as_float(u0.z), __uint_as_float(u0.w));
            p.z = pack_bf16x2(__uint_as_float(u1.x), __uint_as_float(u1.y));
            p.w = pack_bf16x2(__uint_as_float(u1.z), __uint_as_float(u1.w));
            a = __builtin_bit_cast(short8, p);
        }
#pragma unroll
        for (int ct = 0; ct < 8; ++ct) {
            uint4 bu = *(const uint4*)(Wsw + ((size_t)(ct * 4 + ks) * 64 + lane) * 4);
            short8 bfr = __builtin_bit_cast(short8, bu);
            acc[ct] = __builtin_amdgcn_mfma_f32_16x16x32_bf16(a, bfr, acc[ct], 0, 0, 0);
        }
    }

    float dv[4];
#pragma unroll
    for (int r = 0; r < 4; ++r) dv[r] = dinv[min(row0 + q * 4 + r, n - 1)];

#pragma unroll
    for (int ct = 0; ct < 8; ++ct) {
#pragma unroll
        for (int r = 0; r < 4; ++r) {
            int rr = row0 + q * 4 + r;
            if (rr < n)
                outh[(size_t)rr * HID + ct * 16 + m] = f32_to_bf16(acc[ct][r] * dv[r]);
        }
    }
}

// ---------------- aggregation: one wave per node, grouped dwordx4 gather ----------------
// 64 lanes = 4 edge-groups x 16 lanes; xor-butterfly reduce; lanes 0..31 epilogue.
// Output is bf16 (outsh); optional bf16 skip (skipb) added first. In-place
// skipb==outsh is safe (each element read+written by its own thread).

__global__ __launch_bounds__(256) void gnn_aggregate_k(const uint4* __restrict__ h4,
                                const int* __restrict__ rowptr,
                                const int* __restrict__ colidx, const float* __restrict__ dinv,
                                const float* __restrict__ bias,
                                const uint16_t* __restrict__ skipb,
                                uint16_t* __restrict__ outsh, int n) {
    int node = blockIdx.x * 4 + (threadIdx.x >> 6);
    if (node >= n) return;
    int lane = threadIdx.x & 63;
    int g = lane >> 4;
    int sub = lane & 15;
    int beg = rowptr[node];
    int end = rowptr[node + 1];
    float acc[8] = {};
    int e = beg;
    for (; e + 15 < end; e += 16) {
        int j0 = colidx[e + g];
        int j1 = colidx[e + 4 + g];
        int j2 = colidx[e + 8 + g];
        int j3 = colidx[e + 12 + g];
        uint4 u0 = h4[(size_t)j0 * 16 + sub];
        uint4 u1 = h4[(size_t)j1 * 16 + sub];
        uint4 u2 = h4[(size_t)j2 * 16 + sub];
        uint4 u3 = h4[(size_t)j3 * 16 + sub];
        acc[0] += bf_lo(u0.x); acc[1] += bf_hi(u0.x); acc[2] += bf_lo(u0.y); acc[3] += bf_hi(u0.y);
        acc[4] += bf_lo(u0.z); acc[5] += bf_hi(u0.z); acc[6] += bf_lo(u0.w); acc[7] += bf_hi(u0.w);
        acc[0] += bf_lo(u1.x); acc[1] += bf_hi(u1.x); acc[2] += bf_lo(u1.y); acc[3] += bf_hi(u1.y);
        acc[4] += bf_lo(u1.z); acc[5] += bf_hi(u1.z); acc[6] += bf_lo(u1.w); acc[7] += bf_hi(u1.w);
        acc[0] += bf_lo(u2.x); acc[1] += bf_hi(u2.x); acc[2] += bf_lo(u2.y); acc[3] += bf_hi(u2.y);
        acc[4] += bf_lo(u2.z); acc[5] += bf_hi(u2.z); acc[6] += bf_lo(u2.w); acc[7] += bf_hi(u2.w);
        acc[0] += bf_lo(u3.x); acc[1] += bf_hi(u3.x); acc[2] += bf_lo(u3.y); acc[3] += bf_hi(u3.y);
        acc[4] += bf_lo(u3.z); acc[5] += bf_hi(u3.z); acc[6] += bf_lo(u3.w); acc[7] += bf_hi(u3.w);
    }
    for (; e + 3 < end; e += 4) {
        int j = colidx[e + g];
        uint4 u = h4[(size_t)j * 16 + sub];
        acc[0] += bf_lo(u.x); acc[1] += bf_hi(u.x); acc[2] += bf_lo(u.y); acc[3] += bf_hi(u.y);
        acc[4] += bf_lo(u.z); acc[5] += bf_hi(u.z); acc[6] += bf_lo(u.w); acc[7] += bf_hi(u.w);
    }
    if (g < end - e) {
        int j = colidx[e + g];
        uint4 u = h4[(size_t)j * 16 + sub];
        acc[0] += bf_lo(u.x); acc[1] += bf_hi(u.x); acc[2] += bf_lo(u.y); acc[3] += bf_hi(u.y);
        acc[4] += bf_lo(u.z); acc[5] += bf_hi(u.z); acc[6] += bf_lo(u.w); acc[7] += bf_hi(u.w);
    }
#pragma unroll
    for (int k = 0; k < 8; ++k) {
        acc[k] += __shfl_xor(acc[k], 16, 64);
        acc[k] += __shfl_xor(acc[k], 32, 64);
    }
    if (lane < 32) {
        int half = lane >> 4;
        int col = sub * 8 + half * 4;
        float di = dinv[node];
        float4 bv = *(const float4*)(bias + col);
        float o0 = fmaxf(di * acc[half * 4 + 0] + bv.x, 0.0f);
        float o1 = fmaxf(di * acc[half * 4 + 1] + bv.y, 0.0f);
        float o2 = fmaxf(di * acc[half * 4 + 2] + bv.z, 0.0f);
        float o3 = fmaxf(di * acc[half * 4 + 3] + bv.w, 0.0f);
        if (skipb) {
            uint2 sv = *(const uint2*)(skipb + (size_t)node * HID + col);
            o0 += bf_lo(sv.x); o1 += bf_hi(sv.x);
            o2 += bf_lo(sv.y); o3 += bf_hi(sv.y);
        }
        uint2 sh;
        sh.x = pack_bf16x2(o0, o1);
        sh.y = pack_bf16x2(o2, o3);
        *(uint2*)(outsh + (size_t)node * HID + col) = sh;
    }
}

// ---------------- final: bf16 sum[n,128] @ Wc[128,40] + bc -> fp32 ----------------

__global__ __launch_bounds__(320) void gnn_final_k(const uint16_t* __restrict__ sumh,
                                                   const float* __restrict__ wc,
                                                   const float* __restrict__ bc,
                                                   float* __restrict__ out, int n) {
    __shared__ float a[64 * HID];  // 32 KB, float4 block (r, c4) at r*32 + (c4 ^ (r&7))
    const int tx = threadIdx.x % 10;
    const int ty = threadIdx.x / 10;
    const int row0 = blockIdx.x * 64;

    {
        const uint4* S8 = (const uint4*)sumh;  // 8 bf16 per uint4; 16 per row
        float4* s4 = (float4*)a;
        for (int idx = threadIdx.x; idx < 64 * 16; idx += 320) {
            int r = idx >> 4, c8 = idx & 15;
            uint4 v = make_uint4(0u, 0u, 0u, 0u);
            if (row0 + r < n) v = S8[(size_t)(row0 + r) * 16 + c8];
            float4 f0 = make_float4(bf_lo(v.x), bf_hi(v.x), bf_lo(v.y), bf_hi(v.y));
            float4 f1 = make_float4(bf_lo(v.z), bf_hi(v.z), bf_lo(v.w), bf_hi(v.w));
            s4[r * 32 + ((2 * c8) ^ (r & 7))] = f0;
            s4[r * 32 + ((2 * c8 + 1) ^ (r & 7))] = f1;
        }
    }
    __syncthreads();

    float acc[2][4];
    {
        float b0 = bc[tx * 4], b1 = bc[tx * 4 + 1], b2 = bc[tx * 4 + 2], b3 = bc[tx * 4 + 3];
        acc[0][0] = b0; acc[0][1] = b1; acc[0][2] = b2; acc[0][3] = b3;
        acc[1][0] = b0; acc[1][1] = b1; acc[1][2] = b2; acc[1][3] = b3;
    }
    const float* wp = wc + tx * 4;
    const float4* s4 = (const float4*)a;

#pragma unroll 2
    for (int k = 0; k < HID; k += 4) {
        int c4 = k >> 2;
        float ar[2][4];
#pragma unroll
        for (int r = 0; r < 2; ++r) {
            int row = ty * 2 + r;
            *(float4*)&ar[r][0] = s4[row * 32 + (c4 ^ (row & 7))];
        }
#pragma unroll
        for (int kk = 0; kk < 4; ++kk) {
            float4 w = *(const float4*)(wp + (size_t)(k + kk) * OUTD);
#pragma unroll
            for (int r = 0; r < 2; ++r) {
                acc[r][0] += ar[r][kk] * w.x;
                acc[r][1] += ar[r][kk] * w.y;
                acc[r][2] += ar[r][kk] * w.z;
                acc[r][3] += ar[r][kk] * w.w;
            }
        }
    }

#pragma unroll
    for (int r = 0; r < 2; ++r) {
        int row = row0 + ty * 2 + r;
        if (row < n) {
            float4 v = make_float4(acc[r][0], acc[r][1], acc[r][2], acc[r][3]);
            *(float4*)(out + (size_t)row * OUTD + tx * 4) = v;
        }
    }
}

// ---------------- launch ----------------

extern "C" void kernel_launch(void* const* d_in, const int* in_sizes, int n_in,
                              void* d_out, int out_size, void* d_ws, size_t ws_size,
                              hipStream_t stream) {
    const int N = in_sizes[0] / HID;   // 100000
    const int E = in_sizes[7] / 2;     // 1600000

    const float* x  = (const float*)d_in[0];
    const float* W1 = (const float*)d_in[1];
    const float* b1 = (const float*)d_in[2];
    const float* W2 = (const float*)d_in[3];
    const float* b2 = (const float*)d_in[4];
    const float* Wc = (const float*)d_in[5];
    const float* bc = (const float*)d_in[6];
    const int* edges = (const int*)d_in[7];
    float* out = (float*)d_out;

    // workspace carve-up (256B aligned), ~66 MB total
    char* w = (char*)d_ws;
    auto alloc = [&](size_t bytes) -> char* {
        char* p = w;
        w += (bytes + 255) & ~(size_t)255;
        return p;
    };
    uint16_t* hbuf  = (uint16_t*)alloc((size_t)N * HID * 2);  // h' bf16 (both layers)
    uint16_t* bufBh = (uint16_t*)alloc((size_t)N * HID * 2);  // bf16 out1, then bf16 sum
    int*   cnt     = (int*)alloc((size_t)N * 4);
    int*   gcur    = (int*)alloc((size_t)N * 4);
    int*   rowptr  = (int*)alloc((size_t)(N + 1) * 4);
    int*   scanbuf = (int*)alloc((size_t)N * 4);
    int*   bsum    = (int*)alloc(512 * 4);
    int*   pcur    = (int*)alloc(512 * 4);
    int*   colidx  = (int*)alloc((size_t)(E + N) * 4);
    float* dinv    = (float*)alloc((size_t)N * 4);
    uint32_t* pairbuf = (uint32_t*)alloc((size_t)E * 4);
    uint16_t* w1s  = (uint16_t*)alloc(HID * HID * 2);
    uint16_t* w2s  = (uint16_t*)alloc(HID * HID * 2);

    const int nb1 = (N + 255) / 256;   // scan blocks (391)
    const int NB  = (N + 255) >> BSH;  // buckets (391)

    size_t cntspan = (size_t)((char*)rowptr - (char*)cnt);
    hipMemsetAsync(cnt, 0, cntspan, stream);

    gnn_count_k<<<(E + 255) / 256, 256, 0, stream>>>(edges, cnt, E);
    gnn_scan_block_k<<<nb1, 256, 0, stream>>>(cnt, scanbuf, bsum, N);
    gnn_setup_k<<<nb1 + 16, 256, 0, stream>>>(scanbuf, bsum, cnt, rowptr, pcur, dinv,
                                              W1, W2, w1s, w2s, N, nb1);
    gnn_bucket_scatter_k<<<(E + EPB - 1) / EPB, 256, 0, stream>>>(edges, pcur, pairbuf, E, NB);
    gnn_build_csr_k<<<NB, 256, 0, stream>>>(pairbuf, rowptr, colidx, gcur, N);

    // layer 1: h1' = bf16(dinv * (x @ W1)) ; bufBh = bf16(relu(dinv*agg(h1') + b1))
    gnn_gemm_mfma_k<false><<<(N + 63) / 64, 256, 0, stream>>>(x, (const uint32_t*)w1s, dinv, hbuf, N);
    gnn_aggregate_k<<<(N + 3) / 4, 256, 0, stream>>>((const uint4*)hbuf, rowptr, colidx,
                                                     dinv, b1, nullptr, bufBh, N);
    // layer 2: h2' = bf16(dinv * (out1 @ W2)) ; bufBh = bf16(relu(...) + out1) in place
    gnn_gemm_mfma_k<true><<<(N + 63) / 64, 256, 0, stream>>>(bufBh, (const uint32_t*)w2s, dinv, hbuf, N);
    gnn_aggregate_k<<<(N + 3) / 4, 256, 0, stream>>>((const uint4*)hbuf, rowptr, colidx,
                                                     dinv, b2, bufBh, bufBh, N);
    // head
    gnn_final_k<<<(N + 63) / 64, 320, 0, stream>>>(bufBh, Wc, bc, out, N);
}

// Round 11
// 424.666 us; speedup vs baseline: 2.5168x; 1.0018x over previous
//
#include <hip/hip_runtime.h>
#include <stdint.h>

// GNN: 2-layer GCN + skip + classifier head. All fp32 in/out; edge_index int32.
// N=100000, E=1600000, F=H=128, OUT=40.
//
//   h'[j] = dinv[j] * (A_in @ W)[j]  -> bf16, via MFMA 16x16x32 bf16
//   out1 = relu(dinv * agg(h1') + b1)            -> bf16
//   sum  = relu(dinv * agg(h2') + b2) + out1     -> bf16, in place
//   final = sum @ Wc + bc                        -> fp32
//
// Round-9 structure (known good, 425us). Round-10's CSR redesign crashed and is
// reverted; only its f32x2 packed-accumulate (v_pk_add_f32) is re-applied here.

#define HID 128
#define OUTD 40
#define BSH 8                 // 256 nodes per bucket
#define BCAP 6144             // LDS colbuf entries per bucket (mean ~4350)
#define EPB 8192              // edges per scatter block
#define NBMAX 512

typedef __attribute__((ext_vector_type(8))) short short8;
typedef __attribute__((ext_vector_type(4))) float f32x4;
typedef __attribute__((ext_vector_type(2))) float f32x2;

__device__ inline uint16_t f32_to_bf16(float f) {
    uint32_t u = __float_as_uint(f);
    uint32_t r = u + 0x7FFFu + ((u >> 16) & 1u);
    return (uint16_t)(r >> 16);
}
__device__ inline uint32_t pack_bf16x2(float lo, float hi) {
    return (uint32_t)f32_to_bf16(lo) | ((uint32_t)f32_to_bf16(hi) << 16);
}
__device__ inline float bf_lo(uint32_t u) { return __uint_as_float(u << 16); }
__device__ inline float bf_hi(uint32_t u) { return __uint_as_float(u & 0xFFFF0000u); }
// {even col, odd col} of one packed dword — f32x2 so the backend can use v_pk_add_f32
__device__ inline f32x2 up2(uint32_t u) {
    f32x2 r;
    r.x = __uint_as_float(u << 16);
    r.y = __uint_as_float(u & 0xFFFF0000u);
    return r;
}

// ---------------- CSR build ----------------

__global__ void gnn_count_k(const int* __restrict__ edges, int* __restrict__ cnt, int E) {
    int t = blockIdx.x * 256 + threadIdx.x;
    if (t < E) atomicAdd(&cnt[edges[E + t]], 1);
}

__global__ void gnn_scan_block_k(const int* __restrict__ cnt, int* __restrict__ scanbuf,
                                 int* __restrict__ bsum, int n) {
    __shared__ int s[256];
    int i = blockIdx.x * 256 + threadIdx.x;
    int v = (i < n) ? (cnt[i] + 1) : 0;
    s[threadIdx.x] = v;
    __syncthreads();
    for (int off = 1; off < 256; off <<= 1) {
        int t = 0;
        if (threadIdx.x >= off) t = s[threadIdx.x - off];
        __syncthreads();
        if (threadIdx.x >= off) s[threadIdx.x] += t;
        __syncthreads();
    }
    if (i < n) scanbuf[i] = s[threadIdx.x];
    if (threadIdx.x == 255) bsum[blockIdx.x] = s[255];
}

// blocks [0,nbk): rowptr + pcur + dinv (bsum prefix re-reduced per block).
// blocks [nbk, nbk+16): W swizzle fp32 -> bf16 B-fragment order.
// Wsw[((ct*4+ks)*64+lane)*8+j] = bf16(W[(ks*32+(lane>>4)*8+j)*128 + ct*16+(lane&15)])
__global__ __launch_bounds__(256) void gnn_setup_k(const int* __restrict__ scanbuf,
                                                   const int* __restrict__ bsum,
                                                   const int* __restrict__ cnt,
                                                   int* __restrict__ rowptr,
                                                   int* __restrict__ pcur,
                                                   float* __restrict__ dinv,
                                                   const float* __restrict__ W1,
                                                   const float* __restrict__ W2,
                                                   uint16_t* __restrict__ w1s,
                                                   uint16_t* __restrict__ w2s,
                                                   int n, int nbk) {
    int b = blockIdx.x;
    if (b < nbk) {
        __shared__ int red[256];
        int t = threadIdx.x;
        int part = 0;
        for (int i = t; i < b; i += 256) part += bsum[i];
        red[t] = part;
        __syncthreads();
        for (int off = 128; off > 0; off >>= 1) {
            if (t < off) red[t] += red[t + off];
            __syncthreads();
        }
        int off0 = red[0];
        int i = b * 256 + t;
        if (i == 0) { rowptr[0] = 0; pcur[0] = 0; }
        if (i < n) {
            int v = scanbuf[i] + off0;
            rowptr[i + 1] = v;
            if (((i + 1) & 255) == 0) pcur[(i + 1) >> BSH] = v - (i + 1);
            dinv[i] = rsqrtf((float)(cnt[i] + 1));
        }
    } else {
        int wb = b - nbk;                      // 0..15
        const float* W = (wb < 8) ? W1 : W2;
        uint16_t* O = (wb < 8) ? w1s : w2s;
        int t = (wb & 7) * 256 + threadIdx.x;  // 0..2047
        int lane = t & 63;
        int ksct = t >> 6;                     // ct*4+ks
        int nn = (ksct >> 2) * 16 + (lane & 15);
        int k0 = (ksct & 3) * 32 + (lane >> 4) * 8;
        uint32_t d[4];
#pragma unroll
        for (int j = 0; j < 4; ++j)
            d[j] = pack_bf16x2(W[(size_t)(k0 + 2 * j) * HID + nn],
                               W[(size_t)(k0 + 2 * j + 1) * HID + nn]);
        *(uint4*)(O + (size_t)t * 8) = make_uint4(d[0], d[1], d[2], d[3]);
    }
}

__global__ __launch_bounds__(256) void gnn_bucket_scatter_k(const int* __restrict__ edges,
                                                            int* __restrict__ pcur,
                                                            uint32_t* __restrict__ pairbuf,
                                                            int E, int NB) {
    __shared__ int hist[NBMAX];
    int e0 = blockIdx.x * EPB;
    int e1 = min(E, e0 + EPB);
    for (int b = threadIdx.x; b < NB; b += 256) hist[b] = 0;
    __syncthreads();
    for (int e = e0 + threadIdx.x; e < e1; e += 256)
        atomicAdd(&hist[edges[E + e] >> BSH], 1);
    __syncthreads();
    for (int b = threadIdx.x; b < NB; b += 256) {
        int c = hist[b];
        hist[b] = (c > 0) ? atomicAdd(&pcur[b], c) : 0;
    }
    __syncthreads();
    for (int e = e0 + threadIdx.x; e < e1; e += 256) {
        int src = edges[e];
        int dst = edges[E + e];
        int pos = atomicAdd(&hist[dst >> BSH], 1);
        pairbuf[pos] = ((uint32_t)(dst & 255) << 24) | (uint32_t)src;
    }
}

__global__ __launch_bounds__(256) void gnn_build_csr_k(const uint32_t* __restrict__ pairbuf,
                                                       const int* __restrict__ rowptr,
                                                       int* __restrict__ colidx,
                                                       int* __restrict__ gcur, int n) {
    __shared__ int cur[256];
    __shared__ int colbuf[BCAP];
    int b = blockIdx.x;
    int nb0 = b << BSH;
    int nb1 = min(n, nb0 + 256);
    int nn = nb1 - nb0;
    int segbeg = rowptr[nb0];
    int segend = rowptr[nb1];
    int seglen = segend - segbeg;
    int pairbeg = segbeg - nb0;
    int npairs = (segend - nb1) - pairbeg;

    if (seglen <= BCAP) {
        if (threadIdx.x < nn) {
            int node = nb0 + threadIdx.x;
            int rel = rowptr[node] - segbeg;
            colbuf[rel] = node;            // self loop
            cur[threadIdx.x] = rel + 1;
        }
        __syncthreads();
        for (int p = threadIdx.x; p < npairs; p += 256) {
            uint32_t pr = pairbuf[pairbeg + p];
            int pos = atomicAdd(&cur[pr >> 24], 1);
            colbuf[pos] = (int)(pr & 0xFFFFFFu);
        }
        __syncthreads();
        for (int i = threadIdx.x; i < seglen; i += 256)
            colidx[segbeg + i] = colbuf[i];
    } else {
        if (threadIdx.x < nn) {
            int node = nb0 + threadIdx.x;
            colidx[rowptr[node]] = node;
        }
        __syncthreads();
        for (int p = threadIdx.x; p < npairs; p += 256) {
            uint32_t pr = pairbuf[pairbeg + p];
            int dst = nb0 + (int)(pr >> 24);
            int pos = atomicAdd(&gcur[dst], 1);
            colidx[rowptr[dst] + 1 + pos] = (int)(pr & 0xFFFFFFu);
        }
    }
}

// ---------------- MFMA GEMM [n,128] @ [128,128], row-scaled by dinv -> bf16 h' ----------------
// 256 threads = 4 waves x 16 rows. Per wave: 8 col-tiles x 4 K-steps of 16x16x32 bf16.
// A-frag straight from global; ABF16 picks fp32/bf16 A. D: col=lane&15, row=quad*4+reg.

template <bool ABF16>
__global__ __launch_bounds__(256) void gnn_gemm_mfma_k(const void* __restrict__ Aptr,
                                                       const uint32_t* __restrict__ Wsw,
                                                       const float* __restrict__ dinv,
                                                       uint16_t* __restrict__ outh, int n) {
    int wave = threadIdx.x >> 6;
    int lane = threadIdx.x & 63;
    int m = lane & 15;
    int q = lane >> 4;
    int row0 = blockIdx.x * 64 + wave * 16;
    int arow = min(row0 + m, n - 1);

    f32x4 acc[8];
#pragma unroll
    for (int i = 0; i < 8; ++i) acc[i] = (f32x4){0.f, 0.f, 0.f, 0.f};

#pragma unroll
    for (int ks = 0; ks < 4; ++ks) {
        short8 a;
        if (ABF16) {
            const uint16_t* Ab = (const uint16_t*)Aptr;
            uint4 u = *(const uint4*)(Ab + (size_t)arow * HID + ks * 32 + q * 8);
            a = __builtin_bit_cast(short8, u);
        } else {
            const float* Af = (const float*)Aptr + (size_t)arow * HID + ks * 32 + q * 8;
            uint4 u0 = *(const uint4*)(Af);
            uint4 u1 = *(const uint4*)(Af + 4);
            uint4 p;
            p.x = pack_bf16x2(__uint_as_float(u0.x), __uint_as_float(u0.y));
            p.y = pack_bf16x2(__uint_as_float(u0.z), __uint_as_float(u0.w));
            p.z = pack_bf16x2(__uint_as_float(u1.x), __uint_as_float(u1.y));
            p.w = pack_bf16x2(__uint_as_float(u1.z), __uint_as_float(u1.w));
            a = __builtin_bit_cast(short8, p);
        }
#pragma unroll
        for (int ct = 0; ct < 8; ++ct) {
            uint4 bu = *(const uint4*)(Wsw + ((size_t)(ct * 4 + ks) * 64 + lane) * 4);
            short8 bfr = __builtin_bit_cast(short8, bu);
            acc[ct] = __builtin_amdgcn_mfma_f32_16x16x32_bf16(a, bfr, acc[ct], 0, 0, 0);
        }
    }

    float dv[4];
#pragma unroll
    for (int r = 0; r < 4; ++r) dv[r] = dinv[min(row0 + q * 4 + r, n - 1)];

#pragma unroll
    for (int ct = 0; ct < 8; ++ct) {
#pragma unroll
        for (int r = 0; r < 4; ++r) {
            int rr = row0 + q * 4 + r;
            if (rr < n)
                outh[(size_t)rr * HID + ct * 16 + m] = f32_to_bf16(acc[ct][r] * dv[r]);
        }
    }
}

// ---------------- aggregation: one wave per node, grouped dwordx4 gather ----------------
// 64 lanes = 4 edge-groups x 16 lanes; f32x2 packed accumulate (v_pk_add_f32);
// xor-butterfly reduce; lanes 0..31 bf16 epilogue (in-place skip safe).

__global__ __launch_bounds__(256) void gnn_aggregate_k(const uint4* __restrict__ h4,
                                const int* __restrict__ rowptr,
                                const int* __restrict__ colidx, const float* __restrict__ dinv,
                                const float* __restrict__ bias,
                                const uint16_t* __restrict__ skipb,
                                uint16_t* __restrict__ outsh, int n) {
    int node = blockIdx.x * 4 + (threadIdx.x >> 6);
    if (node >= n) return;
    int lane = threadIdx.x & 63;
    int g = lane >> 4;
    int sub = lane & 15;
    int beg = rowptr[node];
    int end = rowptr[node + 1];
    f32x2 acc2[4];
#pragma unroll
    for (int i = 0; i < 4; ++i) acc2[i] = (f32x2){0.f, 0.f};
    int e = beg;
    for (; e + 15 < end; e += 16) {
        int j0 = colidx[e + g];
        int j1 = colidx[e + 4 + g];
        int j2 = colidx[e + 8 + g];
        int j3 = colidx[e + 12 + g];
        uint4 u0 = h4[(size_t)j0 * 16 + sub];
        uint4 u1 = h4[(size_t)j1 * 16 + sub];
        uint4 u2 = h4[(size_t)j2 * 16 + sub];
        uint4 u3 = h4[(size_t)j3 * 16 + sub];
        acc2[0] += up2(u0.x); acc2[1] += up2(u0.y); acc2[2] += up2(u0.z); acc2[3] += up2(u0.w);
        acc2[0] += up2(u1.x); acc2[1] += up2(u1.y); acc2[2] += up2(u1.z); acc2[3] += up2(u1.w);
        acc2[0] += up2(u2.x); acc2[1] += up2(u2.y); acc2[2] += up2(u2.z); acc2[3] += up2(u2.w);
        acc2[0] += up2(u3.x); acc2[1] += up2(u3.y); acc2[2] += up2(u3.z); acc2[3] += up2(u3.w);
    }
    for (; e + 3 < end; e += 4) {
        int j = colidx[e + g];
        uint4 u = h4[(size_t)j * 16 + sub];
        acc2[0] += up2(u.x); acc2[1] += up2(u.y); acc2[2] += up2(u.z); acc2[3] += up2(u.w);
    }
    if (g < end - e) {
        int j = colidx[e + g];
        uint4 u = h4[(size_t)j * 16 + sub];
        acc2[0] += up2(u.x); acc2[1] += up2(u.y); acc2[2] += up2(u.z); acc2[3] += up2(u.w);
    }
    float a8[8];
#pragma unroll
    for (int i = 0; i < 4; ++i) { a8[2 * i] = acc2[i].x; a8[2 * i + 1] = acc2[i].y; }
#pragma unroll
    for (int k = 0; k < 8; ++k) {
        a8[k] += __shfl_xor(a8[k], 16, 64);
        a8[k] += __shfl_xor(a8[k], 32, 64);
    }
    if (lane < 32) {
        int half = lane >> 4;
        int col = sub * 8 + half * 4;
        float di = dinv[node];
        float4 bv = *(const float4*)(bias + col);
        float o0 = fmaxf(di * a8[half * 4 + 0] + bv.x, 0.0f);
        float o1 = fmaxf(di * a8[half * 4 + 1] + bv.y, 0.0f);
        float o2 = fmaxf(di * a8[half * 4 + 2] + bv.z, 0.0f);
        float o3 = fmaxf(di * a8[half * 4 + 3] + bv.w, 0.0f);
        if (skipb) {
            uint2 sv = *(const uint2*)(skipb + (size_t)node * HID + col);
            o0 += bf_lo(sv.x); o1 += bf_hi(sv.x);
            o2 += bf_lo(sv.y); o3 += bf_hi(sv.y);
        }
        uint2 sh;
        sh.x = pack_bf16x2(o0, o1);
        sh.y = pack_bf16x2(o2, o3);
        *(uint2*)(outsh + (size_t)node * HID + col) = sh;
    }
}

// ---------------- final: bf16 sum[n,128] @ Wc[128,40] + bc -> fp32 ----------------

__global__ __launch_bounds__(320) void gnn_final_k(const uint16_t* __restrict__ sumh,
                                                   const float* __restrict__ wc,
                                                   const float* __restrict__ bc,
                                                   float* __restrict__ out, int n) {
    __shared__ float a[64 * HID];  // 32 KB, float4 block (r, c4) at r*32 + (c4 ^ (r&7))
    const int tx = threadIdx.x % 10;
    const int ty = threadIdx.x / 10;
    const int row0 = blockIdx.x * 64;

    {
        const uint4* S8 = (const uint4*)sumh;  // 8 bf16 per uint4; 16 per row
        float4* s4 = (float4*)a;
        for (int idx = threadIdx.x; idx < 64 * 16; idx += 320) {
            int r = idx >> 4, c8 = idx & 15;
            uint4 v = make_uint4(0u, 0u, 0u, 0u);
            if (row0 + r < n) v = S8[(size_t)(row0 + r) * 16 + c8];
            float4 f0 = make_float4(bf_lo(v.x), bf_hi(v.x), bf_lo(v.y), bf_hi(v.y));
            float4 f1 = make_float4(bf_lo(v.z), bf_hi(v.z), bf_lo(v.w), bf_hi(v.w));
            s4[r * 32 + ((2 * c8) ^ (r & 7))] = f0;
            s4[r * 32 + ((2 * c8 + 1) ^ (r & 7))] = f1;
        }
    }
    __syncthreads();

    float acc[2][4];
    {
        float b0 = bc[tx * 4], b1 = bc[tx * 4 + 1], b2 = bc[tx * 4 + 2], b3 = bc[tx * 4 + 3];
        acc[0][0] = b0; acc[0][1] = b1; acc[0][2] = b2; acc[0][3] = b3;
        acc[1][0] = b0; acc[1][1] = b1; acc[1][2] = b2; acc[1][3] = b3;
    }
    const float* wp = wc + tx * 4;
    const float4* s4 = (const float4*)a;

#pragma unroll 2
    for (int k = 0; k < HID; k += 4) {
        int c4 = k >> 2;
        float ar[2][4];
#pragma unroll
        for (int r = 0; r < 2; ++r) {
            int row = ty * 2 + r;
            *(float4*)&ar[r][0] = s4[row * 32 + (c4 ^ (row & 7))];
        }
#pragma unroll
        for (int kk = 0; kk < 4; ++kk) {
            float4 w = *(const float4*)(wp + (size_t)(k + kk) * OUTD);
#pragma unroll
            for (int r = 0; r < 2; ++r) {
                acc[r][0] += ar[r][kk] * w.x;
                acc[r][1] += ar[r][kk] * w.y;
                acc[r][2] += ar[r][kk] * w.z;
                acc[r][3] += ar[r][kk] * w.w;
            }
        }
    }

#pragma unroll
    for (int r = 0; r < 2; ++r) {
        int row = row0 + ty * 2 + r;
        if (row < n) {
            float4 v = make_float4(acc[r][0], acc[r][1], acc[r][2], acc[r][3]);
            *(float4*)(out + (size_t)row * OUTD + tx * 4) = v;
        }
    }
}

// ---------------- launch ----------------

extern "C" void kernel_launch(void* const* d_in, const int* in_sizes, int n_in,
                              void* d_out, int out_size, void* d_ws, size_t ws_size,
                              hipStream_t stream) {
    const int N = in_sizes[0] / HID;   // 100000
    const int E = in_sizes[7] / 2;     // 1600000

    const float* x  = (const float*)d_in[0];
    const float* W1 = (const float*)d_in[1];
    const float* b1 = (const float*)d_in[2];
    const float* W2 = (const float*)d_in[3];
    const float* b2 = (const float*)d_in[4];
    const float* Wc = (const float*)d_in[5];
    const float* bc = (const float*)d_in[6];
    const int* edges = (const int*)d_in[7];
    float* out = (float*)d_out;

    // workspace carve-up (256B aligned), ~66 MB total
    char* w = (char*)d_ws;
    auto alloc = [&](size_t bytes) -> char* {
        char* p = w;
        w += (bytes + 255) & ~(size_t)255;
        return p;
    };
    uint16_t* hbuf  = (uint16_t*)alloc((size_t)N * HID * 2);  // h' bf16 (both layers)
    uint16_t* bufBh = (uint16_t*)alloc((size_t)N * HID * 2);  // bf16 out1, then bf16 sum
    int*   cnt     = (int*)alloc((size_t)N * 4);
    int*   gcur    = (int*)alloc((size_t)N * 4);
    int*   rowptr  = (int*)alloc((size_t)(N + 1) * 4);
    int*   scanbuf = (int*)alloc((size_t)N * 4);
    int*   bsum    = (int*)alloc(512 * 4);
    int*   pcur    = (int*)alloc(512 * 4);
    int*   colidx  = (int*)alloc((size_t)(E + N) * 4);
    float* dinv    = (float*)alloc((size_t)N * 4);
    uint32_t* pairbuf = (uint32_t*)alloc((size_t)E * 4);
    uint16_t* w1s  = (uint16_t*)alloc(HID * HID * 2);
    uint16_t* w2s  = (uint16_t*)alloc(HID * HID * 2);

    const int nb1 = (N + 255) / 256;   // scan blocks (391)
    const int NB  = (N + 255) >> BSH;  // buckets (391)

    size_t cntspan = (size_t)((char*)rowptr - (char*)cnt);
    hipMemsetAsync(cnt, 0, cntspan, stream);

    gnn_count_k<<<(E + 255) / 256, 256, 0, stream>>>(edges, cnt, E);
    gnn_scan_block_k<<<nb1, 256, 0, stream>>>(cnt, scanbuf, bsum, N);
    gnn_setup_k<<<nb1 + 16, 256, 0, stream>>>(scanbuf, bsum, cnt, rowptr, pcur, dinv,
                                              W1, W2, w1s, w2s, N, nb1);
    gnn_bucket_scatter_k<<<(E + EPB - 1) / EPB, 256, 0, stream>>>(edges, pcur, pairbuf, E, NB);
    gnn_build_csr_k<<<NB, 256, 0, stream>>>(pairbuf, rowptr, colidx, gcur, N);

    // layer 1: h1' = bf16(dinv * (x @ W1)) ; bufBh = bf16(relu(dinv*agg(h1') + b1))
    gnn_gemm_mfma_k<false><<<(N + 63) / 64, 256, 0, stream>>>(x, (const uint32_t*)w1s, dinv, hbuf, N);
    gnn_aggregate_k<<<(N + 3) / 4, 256, 0, stream>>>((const uint4*)hbuf, rowptr, colidx,
                                                     dinv, b1, nullptr, bufBh, N);
    // layer 2: h2' = bf16(dinv * (out1 @ W2)) ; bufBh = bf16(relu(...) + out1) in place
    gnn_gemm_mfma_k<true><<<(N + 63) / 64, 256, 0, stream>>>(bufBh, (const uint32_t*)w2s, dinv, hbuf, N);
    gnn_aggregate_k<<<(N + 3) / 4, 256, 0, stream>>>((const uint4*)hbuf, rowptr, colidx,
                                                     dinv, b2, bufBh, bufBh, N);
    // head
    gnn_final_k<<<(N + 63) / 64, 320, 0, stream>>>(bufBh, Wc, bc, out, N);
}